// Round 8
// baseline (805.049 us; speedup 1.0000x reference)
//
#include <hip/hip_runtime.h>
#include <stdint.h>

#define N_TOK 8192
#define DDIM 1024
#define FDIM 4096
#define NEXP 8
#define MAXB1 72                 // 256-row blocks: 16384 + 8*255 padded -> 72
#define MAX_ROWS (MAXB1 * 256)   // 18432

typedef _Float16 half8 __attribute__((ext_vector_type(8)));
typedef float floatx4 __attribute__((ext_vector_type(4)));

#define VMCNT(n) asm volatile("s_waitcnt vmcnt(" #n ")" ::: "memory")
#define LGKM0 asm volatile("s_waitcnt lgkmcnt(0)" ::: "memory")
#define MFMA16(a, b, c) __builtin_amdgcn_mfma_f32_16x16x32_f16(a, b, c, 0, 0, 0)

__device__ __forceinline__ void gload_lds16(const void* g, void* l) {
  __builtin_amdgcn_global_load_lds(
      (const __attribute__((address_space(1))) unsigned int*)(uintptr_t)g,
      (__attribute__((address_space(3))) unsigned int*)(uint32_t)(uintptr_t)l,
      16, 0, 0);
}

// fast exact-enough gelu: tanh form, max |dev| vs erf-gelu ~1e-3
__device__ __forceinline__ float gelu_fast(float v) {
  float u = v * (0.7978845608f + 0.0356774081f * v * v);
  float ev = __expf(2.f * u);
  float th = 1.f - 2.f / (ev + 1.f);  // tanh(u), safe at +/-inf
  return 0.5f * v * (1.f + th);
}

// ---- convert+transpose: fp32 src[R][C] -> fp16 dst[C][R], 64x64 tiles ------
__global__ __launch_bounds__(256) void conv_transpose(
    const float* __restrict__ src, _Float16* __restrict__ dst, int R, int C) {
  __shared__ float t[64][65];
  int e = blockIdx.z;
  const float* s = src + (size_t)e * R * C;
  _Float16* d = dst + (size_t)e * R * C;
  int c0 = blockIdx.x * 64, r0 = blockIdx.y * 64;
  int tid = threadIdx.x;
  int rl = tid >> 4, c4 = (tid & 15) * 4;
#pragma unroll
  for (int i = 0; i < 4; ++i) {
    float4 v = *(const float4*)(s + (size_t)(r0 + rl + i * 16) * C + c0 + c4);
    *(float4*)&t[rl + i * 16][c4] = v;
  }
  __syncthreads();
  int dr = tid >> 2, cc0 = (tid & 3) * 16;  // dst row = src col
#pragma unroll
  for (int h = 0; h < 2; ++h) {
    half8 o;
#pragma unroll
    for (int k = 0; k < 8; ++k) o[k] = (_Float16)t[cc0 + h * 8 + k][dr];
    *(half8*)(d + (size_t)(c0 + dr) * R + r0 + cc0 + h * 8) = o;
  }
}

// ---------------- router: logits, top-2, softmax(fp32), counts --------------
__global__ __launch_bounds__(256) void router_kernel(
    const float* __restrict__ x, const float* __restrict__ rw,
    int* __restrict__ tok_e, float* __restrict__ tok_w, int* __restrict__ meta) {
  __shared__ float srw[NEXP * DDIM];
  int tid = threadIdx.x;
  const float4* rw4 = (const float4*)rw;
  float4* srw4 = (float4*)srw;
#pragma unroll
  for (int i = 0; i < 8; ++i) srw4[tid + i * 256] = rw4[tid + i * 256];
  __syncthreads();

  int wv = tid >> 6, l = tid & 63;
  int t = blockIdx.x * 4 + wv;
  const float4* xr = (const float4*)(x + (size_t)t * DDIM + l * 16);
  float4 xv[4];
#pragma unroll
  for (int i = 0; i < 4; ++i) xv[i] = xr[i];

  float logit[NEXP];
#pragma unroll
  for (int e = 0; e < NEXP; ++e) {
    const float4* wr4 = (const float4*)(srw + e * DDIM + l * 16);
    float acc = 0.f;
#pragma unroll
    for (int i = 0; i < 4; ++i) {
      float4 w4 = wr4[i];
      acc += xv[i].x * w4.x + xv[i].y * w4.y + xv[i].z * w4.z + xv[i].w * w4.w;
    }
#pragma unroll
    for (int off = 32; off > 0; off >>= 1) acc += __shfl_xor(acc, off);
    logit[e] = acc;
  }
  if (l == 0) {
    int i1 = 0;
    float v1 = logit[0];
#pragma unroll
    for (int e = 1; e < NEXP; ++e)
      if (logit[e] > v1) { v1 = logit[e]; i1 = e; }
    int i2 = -1;
    float v2 = -1e30f;
#pragma unroll
    for (int e = 0; e < NEXP; ++e)
      if (e != i1 && logit[e] > v2) { v2 = logit[e]; i2 = e; }
    float ex = expf(v2 - v1);  // v2 <= v1
    float denom = 1.f + ex;
    tok_e[2 * t] = i1;
    tok_e[2 * t + 1] = i2;
    tok_w[2 * t] = 1.f / denom;
    tok_w[2 * t + 1] = ex / denom;
    atomicAdd(&meta[i1], 1);
    atomicAdd(&meta[i2], 1);
  }
}

// ---- offsets: 256-padded segments + block->expert table --------------------
__global__ void offsets_kernel(int* meta) {
  __shared__ int seg[NEXP + 1];
  int l = threadIdx.x;
  if (l == 0) {
    int s = 0;
    for (int e = 0; e < NEXP; ++e) {
      seg[e] = s;
      meta[16 + e] = s;
      meta[8 + e] = s;  // fill cursor starts at segment base
      s += (meta[e] + 255) & ~255;
    }
    seg[NEXP] = s;
    meta[16 + NEXP] = s;
  }
  __syncthreads();
  for (int b = l; b < MAXB1; b += 64) {
    int row = b * 256, ee = -1;
#pragma unroll
    for (int e = 0; e < NEXP; ++e)
      if (row >= seg[e] && row < seg[e + 1]) ee = e;
    meta[32 + b] = ee;
  }
}

// ---- gather: pair -> slot; also inverse map pair -> position ---------------
__global__ void gather_kernel(const int* __restrict__ tok_e, int* meta,
                              int* __restrict__ row_map, int* __restrict__ inv_pos) {
  int p = blockIdx.x * 256 + threadIdx.x;  // 0..16383
  int e = tok_e[p];
  int pos = atomicAdd(&meta[8 + e], 1);
  row_map[pos] = p >> 1;
  inv_pos[p] = pos;
}

// ---- Xg fill: gather x rows as fp16 (zeros for pads) -----------------------
__global__ void xg_fill_kernel(const float* __restrict__ x,
                               const int* __restrict__ row_map,
                               _Float16* __restrict__ Xg) {
  int r = blockIdx.x, t = threadIdx.x;
  int n = row_map[r];
  half8 h = {0, 0, 0, 0, 0, 0, 0, 0};
  if (n >= 0) {
    const float4* s = (const float4*)(x + (size_t)n * DDIM + t * 8);
    float4 a = s[0], b = s[1];
    h[0] = (_Float16)a.x; h[1] = (_Float16)a.y;
    h[2] = (_Float16)a.z; h[3] = (_Float16)a.w;
    h[4] = (_Float16)b.x; h[5] = (_Float16)b.y;
    h[6] = (_Float16)b.z; h[7] = (_Float16)b.w;
  }
  *(half8*)(Xg + (size_t)r * DDIM + t * 8) = h;
}

// ---- grouped GEMM, 256xBNx64, 8 waves, phase-pipelined counted-vmcnt -------
// NF=4 -> BN=256 (4 phases/K-tile, 16 MFMA each); NF=2 -> BN=128 (2 phases,
// 16 MFMA each). LDS rows of 64 fp16, XOR-swizzle byte^((row&7)<<4) on both
// stage (inverse-swizzled global src) and ds_read. Region staging schedule:
//  A-alpha0 = row-chunks {0,2} (mh0 of both wm halves), A-alpha1 = {1,3}.
//  NF4: p0 reads B(all)+A(mh0,kk0), stages a1(t+1); p1 reads A(mh0,kk1),
//       stages B(t+2)[0,1], VMCNT(10); p2 reads A(mh1,kk0), stages B(t+2)[2,3];
//       p3 reads A(mh1,kk1), stages a0(t+2), VMCNT(8).
//  NF2: p0 reads B(all)+A(mh0,kk01), stages a1(t+1), VMCNT(6);
//       p1 reads A(mh1,kk01), stages B(t+2)+a0(t+2), VMCNT(6).
// Every region is staged >=1 barrier-pair after its last read (WAR-safe);
// every read is covered by a counted vmcnt before an earlier barrier.
template <int NF, int EPI>
__global__ __launch_bounds__(512, 2) void gemm8p(
    const _Float16* __restrict__ A, const _Float16* __restrict__ Bbase,
    const int* __restrict__ be, int lyt, size_t lda, size_t ldb, int nt,
    long long b_estride, _Float16* __restrict__ Hout, int ldh,
    float* __restrict__ Yout, int accum) {
  constexpr int BN = NF * 64;
  int o = blockIdx.x, nb = gridDim.x;
  int q = nb >> 3, r8 = nb & 7, xc = o & 7, oo = o >> 3;
  int wg = (xc < r8 ? xc * (q + 1) : r8 * (q + 1) + (xc - r8) * q) + oo;
  int by = wg & ((1 << lyt) - 1);
  int bx = wg >> lyt;
  int e = be[bx];
  if (e < 0) return;

  __shared__ __align__(16) _Float16 sA[2][256 * 64];
  __shared__ __align__(16) _Float16 sB[2][BN * 64];

  const _Float16* Ab = A + (size_t)bx * 256 * lda;
  const _Float16* Bb = Bbase + (size_t)e * b_estride + (size_t)by * BN * ldb;

  int tid = threadIdx.x, l = tid & 63, wid = tid >> 6;
  int wm = wid >> 2, wn = wid & 3;
  int rbA = wm * 128 + (l & 15);
  int cbB = wn * (BN / 4) + (l & 15);
  int sw = (l & 7) << 4;
  int ko0 = (((l >> 4) << 4) ^ sw) >> 1;         // fp16 elems, kk=0
  int ko1 = ((64 + ((l >> 4) << 4)) ^ sw) >> 1;  // kk=1
  int srow = tid >> 3;                           // 0..63 within a 64-row chunk
  int scol = ((((tid & 7) << 4) ^ ((srow & 7) << 4)) >> 1);

  floatx4 acc[8][NF] = {};

  auto stA = [&](int t, int half) {  // A chunks {half, half+2} of tile t
    const _Float16* src = Ab + (size_t)t * 64;
    _Float16* dst = sA[t & 1];
    gload_lds16(src + (size_t)(half * 64 + srow) * lda + scol,
                dst + half * 4096 + tid * 8);
    gload_lds16(src + (size_t)((half + 2) * 64 + srow) * lda + scol,
                dst + (half + 2) * 4096 + tid * 8);
  };
  auto stB = [&](int t, int c0) {  // B chunks {c0, c0+1} of tile t
    const _Float16* src = Bb + (size_t)t * 64;
    _Float16* dst = sB[t & 1];
    gload_lds16(src + (size_t)(c0 * 64 + srow) * ldb + scol,
                dst + c0 * 4096 + tid * 8);
    gload_lds16(src + (size_t)((c0 + 1) * 64 + srow) * ldb + scol,
                dst + (c0 + 1) * 4096 + tid * 8);
  };

  // prologue issue order: B(0), a0(0), a1(0), B(1), a0(1)
  stB(0, 0); if constexpr (NF == 4) stB(0, 2);
  stA(0, 0);
  stA(0, 1);
  stB(1, 0); if constexpr (NF == 4) stB(1, 2);
  stA(1, 0);
  if constexpr (NF == 4) { VMCNT(8); } else { VMCNT(6); }
  __builtin_amdgcn_s_barrier();

  for (int t = 0; t < nt; ++t) {
    const _Float16* sAb = sA[t & 1];
    const _Float16* sBb = sB[t & 1];
    int t1 = t + 1; if (t1 >= nt) t1 -= nt;  // nt even -> parity preserved
    int t2 = t + 2; if (t2 >= nt) t2 -= nt;
    half8 bf[NF][2], af[4];

    if constexpr (NF == 4) {
      // ---- phase 0: read B(all)+A(mh0,kk0); stage a1(t+1) ----
#pragma unroll
      for (int n = 0; n < 4; ++n) {
        bf[n][0] = *(const half8*)&sBb[(cbB + n * 16) * 64 + ko0];
        bf[n][1] = *(const half8*)&sBb[(cbB + n * 16) * 64 + ko1];
      }
#pragma unroll
      for (int m = 0; m < 4; ++m) af[m] = *(const half8*)&sAb[(rbA + m * 16) * 64 + ko0];
      stA(t1, 1);
      __builtin_amdgcn_s_barrier();
      LGKM0; __builtin_amdgcn_sched_barrier(0);
      __builtin_amdgcn_s_setprio(1);
#pragma unroll
      for (int m = 0; m < 4; ++m)
#pragma unroll
        for (int n = 0; n < 4; ++n) acc[m][n] = MFMA16(af[m], bf[n][0], acc[m][n]);
      __builtin_amdgcn_s_setprio(0);
      __builtin_amdgcn_s_barrier();
      // ---- phase 1: read A(mh0,kk1); stage B(t+2)[0,1]; VMCNT(10) ----
#pragma unroll
      for (int m = 0; m < 4; ++m) af[m] = *(const half8*)&sAb[(rbA + m * 16) * 64 + ko1];
      stB(t2, 0);
      VMCNT(10);
      __builtin_amdgcn_s_barrier();
      LGKM0; __builtin_amdgcn_sched_barrier(0);
      __builtin_amdgcn_s_setprio(1);
#pragma unroll
      for (int m = 0; m < 4; ++m)
#pragma unroll
        for (int n = 0; n < 4; ++n) acc[m][n] = MFMA16(af[m], bf[n][1], acc[m][n]);
      __builtin_amdgcn_s_setprio(0);
      __builtin_amdgcn_s_barrier();
      // ---- phase 2: read A(mh1,kk0); stage B(t+2)[2,3] ----
#pragma unroll
      for (int m = 0; m < 4; ++m) af[m] = *(const half8*)&sAb[(rbA + 64 + m * 16) * 64 + ko0];
      stB(t2, 2);
      __builtin_amdgcn_s_barrier();
      LGKM0; __builtin_amdgcn_sched_barrier(0);
      __builtin_amdgcn_s_setprio(1);
#pragma unroll
      for (int m = 0; m < 4; ++m)
#pragma unroll
        for (int n = 0; n < 4; ++n) acc[4 + m][n] = MFMA16(af[m], bf[n][0], acc[4 + m][n]);
      __builtin_amdgcn_s_setprio(0);
      __builtin_amdgcn_s_barrier();
      // ---- phase 3: read A(mh1,kk1); stage a0(t+2); VMCNT(8) ----
#pragma unroll
      for (int m = 0; m < 4; ++m) af[m] = *(const half8*)&sAb[(rbA + 64 + m * 16) * 64 + ko1];
      stA(t2, 0);
      VMCNT(8);
      __builtin_amdgcn_s_barrier();
      LGKM0; __builtin_amdgcn_sched_barrier(0);
      __builtin_amdgcn_s_setprio(1);
#pragma unroll
      for (int m = 0; m < 4; ++m)
#pragma unroll
        for (int n = 0; n < 4; ++n) acc[4 + m][n] = MFMA16(af[m], bf[n][1], acc[4 + m][n]);
      __builtin_amdgcn_s_setprio(0);
      __builtin_amdgcn_s_barrier();
    } else {
      half8 ag[4];
      // ---- phase 0: read B(all)+A(mh0,kk01); stage a1(t+1); VMCNT(6) ----
#pragma unroll
      for (int n = 0; n < 2; ++n) {
        bf[n][0] = *(const half8*)&sBb[(cbB + n * 16) * 64 + ko0];
        bf[n][1] = *(const half8*)&sBb[(cbB + n * 16) * 64 + ko1];
      }
#pragma unroll
      for (int m = 0; m < 4; ++m) {
        af[m] = *(const half8*)&sAb[(rbA + m * 16) * 64 + ko0];
        ag[m] = *(const half8*)&sAb[(rbA + m * 16) * 64 + ko1];
      }
      stA(t1, 1);
      VMCNT(6);
      __builtin_amdgcn_s_barrier();
      LGKM0; __builtin_amdgcn_sched_barrier(0);
      __builtin_amdgcn_s_setprio(1);
#pragma unroll
      for (int m = 0; m < 4; ++m)
#pragma unroll
        for (int n = 0; n < 2; ++n) {
          acc[m][n] = MFMA16(af[m], bf[n][0], acc[m][n]);
          acc[m][n] = MFMA16(ag[m], bf[n][1], acc[m][n]);
        }
      __builtin_amdgcn_s_setprio(0);
      __builtin_amdgcn_s_barrier();
      // ---- phase 1: read A(mh1,kk01); stage B(t+2)+a0(t+2); VMCNT(6) ----
#pragma unroll
      for (int m = 0; m < 4; ++m) {
        af[m] = *(const half8*)&sAb[(rbA + 64 + m * 16) * 64 + ko0];
        ag[m] = *(const half8*)&sAb[(rbA + 64 + m * 16) * 64 + ko1];
      }
      stB(t2, 0);
      stA(t2, 0);
      VMCNT(6);
      __builtin_amdgcn_s_barrier();
      LGKM0; __builtin_amdgcn_sched_barrier(0);
      __builtin_amdgcn_s_setprio(1);
#pragma unroll
      for (int m = 0; m < 4; ++m)
#pragma unroll
        for (int n = 0; n < 2; ++n) {
          acc[4 + m][n] = MFMA16(af[m], bf[n][0], acc[4 + m][n]);
          acc[4 + m][n] = MFMA16(ag[m], bf[n][1], acc[4 + m][n]);
        }
      __builtin_amdgcn_s_setprio(0);
      __builtin_amdgcn_s_barrier();
    }
  }
  VMCNT(0);  // drain wrapped tail prefetches before exit

  if (EPI == 0) {
#pragma unroll
    for (int m = 0; m < 8; ++m) {
#pragma unroll
      for (int j = 0; j < 4; ++j) {
        size_t r = (size_t)bx * 256 + wm * 128 + m * 16 + (l >> 4) * 4 + j;
        _Float16* hp = Hout + r * ldh + (size_t)by * BN + wn * (BN / 4) + (l & 15);
#pragma unroll
        for (int n = 0; n < NF; ++n) hp[n * 16] = (_Float16)gelu_fast(acc[m][n][j]);
      }
    }
  } else {
#pragma unroll
    for (int m = 0; m < 8; ++m) {
#pragma unroll
      for (int j = 0; j < 4; ++j) {
        size_t r = (size_t)bx * 256 + wm * 128 + m * 16 + (l >> 4) * 4 + j;
        float* yp = Yout + r * DDIM + (size_t)by * BN + wn * (BN / 4) + (l & 15);
        if (accum) {
#pragma unroll
          for (int n = 0; n < NF; ++n) yp[n * 16] += acc[m][n][j];
        } else {
#pragma unroll
          for (int n = 0; n < NF; ++n) yp[n * 16] = acc[m][n][j];
        }
      }
    }
  }
}

// ---- combine: out[t] = w0 * Y[pos0] + w1 * Y[pos1] -------------------------
__global__ __launch_bounds__(128) void combine_kernel(
    const float* __restrict__ Y, const int* __restrict__ inv_pos,
    const float* __restrict__ tok_w, float* __restrict__ out) {
  int t = blockIdx.x, l = threadIdx.x;
  int p0 = inv_pos[2 * t], p1 = inv_pos[2 * t + 1];
  float w0 = tok_w[2 * t], w1 = tok_w[2 * t + 1];
  const float4* y0 = (const float4*)(Y + (size_t)p0 * DDIM) + l * 2;
  const float4* y1 = (const float4*)(Y + (size_t)p1 * DDIM) + l * 2;
  float4* o = (float4*)(out + (size_t)t * DDIM) + l * 2;
#pragma unroll
  for (int i = 0; i < 2; ++i) {
    float4 a = y0[i], b = y1[i];
    float4 r;
    r.x = w0 * a.x + w1 * b.x;
    r.y = w0 * a.y + w1 * b.y;
    r.z = w0 * a.z + w1 * b.z;
    r.w = w0 * a.w + w1 * b.w;
    o[i] = r;
  }
}

// ---------------- launch -----------------------------------------------------
extern "C" void kernel_launch(void* const* d_in, const int* in_sizes, int n_in,
                              void* d_out, int out_size, void* d_ws, size_t ws_size,
                              hipStream_t stream) {
  const float* x = (const float*)d_in[0];
  const float* rw = (const float*)d_in[1];
  const float* w1 = (const float*)d_in[2];
  const float* w2 = (const float*)d_in[3];
  float* out = (float*)d_out;

  char* base = (char*)d_ws;
  size_t off = 0;
  auto alloc = [&](size_t bytes) {
    void* p = base + off;
    off += (bytes + 255) & ~(size_t)255;
    return p;
  };
  _Float16* w1t = (_Float16*)alloc((size_t)NEXP * FDIM * DDIM * 2);
  _Float16* w2t = (_Float16*)alloc((size_t)NEXP * DDIM * FDIM * 2);
  _Float16* Xg = (_Float16*)alloc((size_t)MAX_ROWS * DDIM * 2);
  float* Y = (float*)alloc((size_t)MAX_ROWS * DDIM * 4);
  int* row_map = (int*)alloc(MAX_ROWS * 4);
  int* inv_pos = (int*)alloc(N_TOK * 2 * 4);
  int* tok_e = (int*)alloc(N_TOK * 2 * 4);
  float* tok_w = (float*)alloc(N_TOK * 2 * 4);
  int* meta = (int*)alloc(1024);
  size_t fixed = off;

  // F-chunking so the H buffer fits the provided workspace. Fc >= 256 always.
  int NC = 1;
  while (NC < 16 && fixed + (size_t)MAX_ROWS * (FDIM / NC) * 2 > ws_size) NC *= 2;
  int Fc = FDIM / NC;
  _Float16* H = (_Float16*)alloc((size_t)MAX_ROWS * Fc * 2);

  hipMemsetAsync(meta, 0, 64, stream);                  // counts + fill
  hipMemsetAsync(row_map, 0xFF, MAX_ROWS * 4, stream);  // -1 sentinels

  conv_transpose<<<dim3(FDIM / 64, DDIM / 64, NEXP), 256, 0, stream>>>(w1, w1t, DDIM, FDIM);
  conv_transpose<<<dim3(DDIM / 64, FDIM / 64, NEXP), 256, 0, stream>>>(w2, w2t, FDIM, DDIM);
  router_kernel<<<N_TOK / 4, 256, 0, stream>>>(x, rw, tok_e, tok_w, meta);
  offsets_kernel<<<1, 64, 0, stream>>>(meta);
  gather_kernel<<<N_TOK * 2 / 256, 256, 0, stream>>>(tok_e, meta, row_map, inv_pos);
  xg_fill_kernel<<<MAX_ROWS, 128, 0, stream>>>(x, row_map, Xg);

  const int* be = meta + 32;
  int yt1 = Fc / 256;                        // power of two (1..16)
  int ly1 = 31 - __builtin_clz(yt1);
  for (int c = 0; c < NC; ++c) {
    // GEMM1: Xg[M,1024] x w1t[e][Fc,1024]^T -> gelu -> H[M,Fc]   (BN=256)
    gemm8p<4, 0><<<dim3(MAXB1 * yt1), 512, 0, stream>>>(
        Xg, w1t + (size_t)c * Fc * DDIM, be, ly1,
        (size_t)DDIM, (size_t)DDIM, DDIM / 64, (long long)FDIM * DDIM,
        H, Fc, nullptr, 0);
    // GEMM2: H[M,Fc] x w2t[e][1024,FDIM(slice c)]^T -> Y[M,1024]  (BN=128)
    gemm8p<2, 1><<<dim3(MAXB1 * 8), 512, 0, stream>>>(
        H, w2t + (size_t)c * Fc, be, 3,
        (size_t)Fc, (size_t)FDIM, Fc / 64, (long long)DDIM * FDIM,
        nullptr, 0, Y, c > 0);
  }
  combine_kernel<<<N_TOK, 128, 0, stream>>>(Y, inv_pos, tok_w, out);
}

// Round 9
// 776.261 us; speedup vs baseline: 1.0371x; 1.0371x over previous
//
#include <hip/hip_runtime.h>
#include <stdint.h>

#define N_TOK 8192
#define DDIM 1024
#define FDIM 4096
#define NEXP 8
#define MAXB1 72                 // 256-row blocks: 16384 + 8*255 padded -> 72
#define MAX_ROWS (MAXB1 * 256)   // 18432

typedef _Float16 half8 __attribute__((ext_vector_type(8)));
typedef float floatx4 __attribute__((ext_vector_type(4)));

#define VMCNT(n) asm volatile("s_waitcnt vmcnt(" #n ")" ::: "memory")
#define LGKM0 asm volatile("s_waitcnt lgkmcnt(0)" ::: "memory")
#define MFMA16(a, b, c) __builtin_amdgcn_mfma_f32_16x16x32_f16(a, b, c, 0, 0, 0)

__device__ __forceinline__ void gload_lds16(const void* g, void* l) {
  __builtin_amdgcn_global_load_lds(
      (const __attribute__((address_space(1))) unsigned int*)(uintptr_t)g,
      (__attribute__((address_space(3))) unsigned int*)(uint32_t)(uintptr_t)l,
      16, 0, 0);
}

// fast exact-enough gelu: tanh form, max |dev| vs erf-gelu ~1e-3
__device__ __forceinline__ float gelu_fast(float v) {
  float u = v * (0.7978845608f + 0.0356774081f * v * v);
  float ev = __expf(2.f * u);
  float th = 1.f - 2.f / (ev + 1.f);  // tanh(u), safe at +/-inf
  return 0.5f * v * (1.f + th);
}

// ---- convert+transpose: fp32 src[R][C] -> fp16 dst[C][R], 64x64 tiles ------
__global__ __launch_bounds__(256) void conv_transpose(
    const float* __restrict__ src, _Float16* __restrict__ dst, int R, int C) {
  __shared__ float t[64][65];
  int e = blockIdx.z;
  const float* s = src + (size_t)e * R * C;
  _Float16* d = dst + (size_t)e * R * C;
  int c0 = blockIdx.x * 64, r0 = blockIdx.y * 64;
  int tid = threadIdx.x;
  int rl = tid >> 4, c4 = (tid & 15) * 4;
#pragma unroll
  for (int i = 0; i < 4; ++i) {
    float4 v = *(const float4*)(s + (size_t)(r0 + rl + i * 16) * C + c0 + c4);
    *(float4*)&t[rl + i * 16][c4] = v;
  }
  __syncthreads();
  int dr = tid >> 2, cc0 = (tid & 3) * 16;  // dst row = src col
#pragma unroll
  for (int h = 0; h < 2; ++h) {
    half8 o;
#pragma unroll
    for (int k = 0; k < 8; ++k) o[k] = (_Float16)t[cc0 + h * 8 + k][dr];
    *(half8*)(d + (size_t)(c0 + dr) * R + r0 + cc0 + h * 8) = o;
  }
}

// ---------------- router: logits, top-2, softmax(fp32), counts --------------
__global__ __launch_bounds__(256) void router_kernel(
    const float* __restrict__ x, const float* __restrict__ rw,
    int* __restrict__ tok_e, float* __restrict__ tok_w, int* __restrict__ meta) {
  __shared__ float srw[NEXP * DDIM];
  int tid = threadIdx.x;
  const float4* rw4 = (const float4*)rw;
  float4* srw4 = (float4*)srw;
#pragma unroll
  for (int i = 0; i < 8; ++i) srw4[tid + i * 256] = rw4[tid + i * 256];
  __syncthreads();

  int wv = tid >> 6, l = tid & 63;
  int t = blockIdx.x * 4 + wv;
  const float4* xr = (const float4*)(x + (size_t)t * DDIM + l * 16);
  float4 xv[4];
#pragma unroll
  for (int i = 0; i < 4; ++i) xv[i] = xr[i];

  float logit[NEXP];
#pragma unroll
  for (int e = 0; e < NEXP; ++e) {
    const float4* wr4 = (const float4*)(srw + e * DDIM + l * 16);
    float acc = 0.f;
#pragma unroll
    for (int i = 0; i < 4; ++i) {
      float4 w4 = wr4[i];
      acc += xv[i].x * w4.x + xv[i].y * w4.y + xv[i].z * w4.z + xv[i].w * w4.w;
    }
#pragma unroll
    for (int off = 32; off > 0; off >>= 1) acc += __shfl_xor(acc, off);
    logit[e] = acc;
  }
  if (l == 0) {
    int i1 = 0;
    float v1 = logit[0];
#pragma unroll
    for (int e = 1; e < NEXP; ++e)
      if (logit[e] > v1) { v1 = logit[e]; i1 = e; }
    int i2 = -1;
    float v2 = -1e30f;
#pragma unroll
    for (int e = 0; e < NEXP; ++e)
      if (e != i1 && logit[e] > v2) { v2 = logit[e]; i2 = e; }
    float ex = expf(v2 - v1);  // v2 <= v1
    float denom = 1.f + ex;
    tok_e[2 * t] = i1;
    tok_e[2 * t + 1] = i2;
    tok_w[2 * t] = 1.f / denom;
    tok_w[2 * t + 1] = ex / denom;
    atomicAdd(&meta[i1], 1);
    atomicAdd(&meta[i2], 1);
  }
}

// ---- offsets: 256-padded segments + block->expert table --------------------
__global__ void offsets_kernel(int* meta) {
  __shared__ int seg[NEXP + 1];
  int l = threadIdx.x;
  if (l == 0) {
    int s = 0;
    for (int e = 0; e < NEXP; ++e) {
      seg[e] = s;
      meta[16 + e] = s;
      meta[8 + e] = s;  // fill cursor starts at segment base
      s += (meta[e] + 255) & ~255;
    }
    seg[NEXP] = s;
    meta[16 + NEXP] = s;
  }
  __syncthreads();
  for (int b = l; b < MAXB1; b += 64) {
    int row = b * 256, ee = -1;
#pragma unroll
    for (int e = 0; e < NEXP; ++e)
      if (row >= seg[e] && row < seg[e + 1]) ee = e;
    meta[32 + b] = ee;
  }
}

// ---- gather: pair -> slot; also inverse map pair -> position ---------------
__global__ void gather_kernel(const int* __restrict__ tok_e, int* meta,
                              int* __restrict__ row_map, int* __restrict__ inv_pos) {
  int p = blockIdx.x * 256 + threadIdx.x;  // 0..16383
  int e = tok_e[p];
  int pos = atomicAdd(&meta[8 + e], 1);
  row_map[pos] = p >> 1;
  inv_pos[p] = pos;
}

// ---- Xg fill: gather x rows as fp16 (zeros for pads) -----------------------
__global__ void xg_fill_kernel(const float* __restrict__ x,
                               const int* __restrict__ row_map,
                               _Float16* __restrict__ Xg) {
  int r = blockIdx.x, t = threadIdx.x;
  int n = row_map[r];
  half8 h = {0, 0, 0, 0, 0, 0, 0, 0};
  if (n >= 0) {
    const float4* s = (const float4*)(x + (size_t)n * DDIM + t * 8);
    float4 a = s[0], b = s[1];
    h[0] = (_Float16)a.x; h[1] = (_Float16)a.y;
    h[2] = (_Float16)a.z; h[3] = (_Float16)a.w;
    h[4] = (_Float16)b.x; h[5] = (_Float16)b.y;
    h[6] = (_Float16)b.z; h[7] = (_Float16)b.w;
  }
  *(half8*)(Xg + (size_t)r * DDIM + t * 8) = h;
}

// ---- grouped GEMM, 256x256x64, 8 waves, 4-phase counted-vmcnt pipeline -----
// Block mapping: 4x4 supergroups (4 bx x 4 columns) so each group's operand
// footprint (2MB A + 2MB B) fits one XCD L2; groups XCD-swizzled bijectively,
// gx-fastest so the B-quad stays L2-resident across the chunk.
// EPI=0: c = by (N columns of Fc); gelu -> Hout fp16.
// EPI=1: c = (by = c&3, bz = c>>2 K-quarter); fp16 store/accum into Yq slab.
template <int EPI>
__global__ __launch_bounds__(512, 2) void gemmG(
    const _Float16* __restrict__ A, const _Float16* __restrict__ Bbase,
    const int* __restrict__ be, int nbx, size_t lda, size_t ldb, int nt,
    long long b_estride, size_t kqk,
    _Float16* __restrict__ Hout, int ldh,
    _Float16* __restrict__ Yq, size_t yzstride, int accum) {
  // ---- supergroup mapping ----
  int wg = blockIdx.x;
  int g = wg >> 4, r = wg & 15;
  int ngr = (int)gridDim.x >> 4;
  int q = ngr >> 3, r8 = ngr & 7, xcg = g & 7, og = g >> 3;
  int gs = (xcg < r8 ? xcg * (q + 1) : r8 * (q + 1) + (xcg - r8) * q) + og;
  int ngx = nbx >> 2;
  int gx = gs % ngx, gy = gs / ngx;
  int bx = gx * 4 + (r & 3);
  int c = gy * 4 + (r >> 2);
  int e = be[bx];
  if (e < 0) return;
  int by, bz;
  if (EPI == 1) { by = c & 3; bz = c >> 2; } else { by = c; bz = 0; }

  __shared__ __align__(16) _Float16 sA[2][256 * 64];
  __shared__ __align__(16) _Float16 sB[2][256 * 64];

  const _Float16* Ab = A + (size_t)bx * 256 * lda + (size_t)bz * kqk;
  const _Float16* Bb = Bbase + (size_t)e * b_estride + (size_t)by * 256 * ldb + (size_t)bz * kqk;

  int tid = threadIdx.x, l = tid & 63, wid = tid >> 6;
  int wm = wid >> 2, wn = wid & 3;
  int rbA = wm * 128 + (l & 15);
  int cbB = wn * 64 + (l & 15);
  int sw = (l & 7) << 4;
  int ko0 = (((l >> 4) << 4) ^ sw) >> 1;         // fp16 elems, kk=0
  int ko1 = ((64 + ((l >> 4) << 4)) ^ sw) >> 1;  // kk=1
  int srow = tid >> 3;                           // 0..63 within a 64-row chunk
  int scol = ((((tid & 7) << 4) ^ ((srow & 7) << 4)) >> 1);

  floatx4 acc[8][4] = {};

  auto stA = [&](int t, int half) {  // A chunks {half, half+2} of tile t
    const _Float16* src = Ab + (size_t)t * 64;
    _Float16* dst = sA[t & 1];
    gload_lds16(src + (size_t)(half * 64 + srow) * lda + scol,
                dst + half * 4096 + tid * 8);
    gload_lds16(src + (size_t)((half + 2) * 64 + srow) * lda + scol,
                dst + (half + 2) * 4096 + tid * 8);
  };
  auto stB = [&](int t, int c0) {  // B chunks {c0, c0+1} of tile t
    const _Float16* src = Bb + (size_t)t * 64;
    _Float16* dst = sB[t & 1];
    gload_lds16(src + (size_t)(c0 * 64 + srow) * ldb + scol,
                dst + c0 * 4096 + tid * 8);
    gload_lds16(src + (size_t)((c0 + 1) * 64 + srow) * ldb + scol,
                dst + (c0 + 1) * 4096 + tid * 8);
  };

  // prologue issue order: B(0), a0(0), a1(0), B(1), a0(1)
  stB(0, 0); stB(0, 2);
  stA(0, 0);
  stA(0, 1);
  stB(1, 0); stB(1, 2);
  stA(1, 0);
  VMCNT(8);
  __builtin_amdgcn_s_barrier();

  for (int t = 0; t < nt; ++t) {
    const _Float16* sAb = sA[t & 1];
    const _Float16* sBb = sB[t & 1];
    int t1 = t + 1; if (t1 >= nt) t1 -= nt;  // nt even -> parity preserved
    int t2 = t + 2; if (t2 >= nt) t2 -= nt;
    half8 bf[4][2], af[4];

    // ---- phase 0: read B(all)+A(mh0,kk0); stage a1(t+1) ----
#pragma unroll
    for (int n = 0; n < 4; ++n) {
      bf[n][0] = *(const half8*)&sBb[(cbB + n * 16) * 64 + ko0];
      bf[n][1] = *(const half8*)&sBb[(cbB + n * 16) * 64 + ko1];
    }
#pragma unroll
    for (int m = 0; m < 4; ++m) af[m] = *(const half8*)&sAb[(rbA + m * 16) * 64 + ko0];
    stA(t1, 1);
    __builtin_amdgcn_s_barrier();
    LGKM0; __builtin_amdgcn_sched_barrier(0);
    __builtin_amdgcn_s_setprio(1);
#pragma unroll
    for (int m = 0; m < 4; ++m)
#pragma unroll
      for (int n = 0; n < 4; ++n) acc[m][n] = MFMA16(af[m], bf[n][0], acc[m][n]);
    __builtin_amdgcn_s_setprio(0);
    __builtin_amdgcn_s_barrier();
    // ---- phase 1: read A(mh0,kk1); stage B(t+2)[0,1]; VMCNT(10) ----
#pragma unroll
    for (int m = 0; m < 4; ++m) af[m] = *(const half8*)&sAb[(rbA + m * 16) * 64 + ko1];
    stB(t2, 0);
    VMCNT(10);
    __builtin_amdgcn_s_barrier();
    LGKM0; __builtin_amdgcn_sched_barrier(0);
    __builtin_amdgcn_s_setprio(1);
#pragma unroll
    for (int m = 0; m < 4; ++m)
#pragma unroll
      for (int n = 0; n < 4; ++n) acc[m][n] = MFMA16(af[m], bf[n][1], acc[m][n]);
    __builtin_amdgcn_s_setprio(0);
    __builtin_amdgcn_s_barrier();
    // ---- phase 2: read A(mh1,kk0); stage B(t+2)[2,3] ----
#pragma unroll
    for (int m = 0; m < 4; ++m) af[m] = *(const half8*)&sAb[(rbA + 64 + m * 16) * 64 + ko0];
    stB(t2, 2);
    __builtin_amdgcn_s_barrier();
    LGKM0; __builtin_amdgcn_sched_barrier(0);
    __builtin_amdgcn_s_setprio(1);
#pragma unroll
    for (int m = 0; m < 4; ++m)
#pragma unroll
      for (int n = 0; n < 4; ++n) acc[4 + m][n] = MFMA16(af[m], bf[n][0], acc[4 + m][n]);
    __builtin_amdgcn_s_setprio(0);
    __builtin_amdgcn_s_barrier();
    // ---- phase 3: read A(mh1,kk1); stage a0(t+2); VMCNT(8) ----
#pragma unroll
    for (int m = 0; m < 4; ++m) af[m] = *(const half8*)&sAb[(rbA + 64 + m * 16) * 64 + ko1];
    stA(t2, 0);
    VMCNT(8);
    __builtin_amdgcn_s_barrier();
    LGKM0; __builtin_amdgcn_sched_barrier(0);
    __builtin_amdgcn_s_setprio(1);
#pragma unroll
    for (int m = 0; m < 4; ++m)
#pragma unroll
      for (int n = 0; n < 4; ++n) acc[4 + m][n] = MFMA16(af[m], bf[n][1], acc[4 + m][n]);
    __builtin_amdgcn_s_setprio(0);
    __builtin_amdgcn_s_barrier();
  }
  VMCNT(0);  // drain wrapped tail prefetches before exit

  if (EPI == 0) {
#pragma unroll
    for (int m = 0; m < 8; ++m) {
#pragma unroll
      for (int j = 0; j < 4; ++j) {
        size_t rr = (size_t)bx * 256 + wm * 128 + m * 16 + (l >> 4) * 4 + j;
        _Float16* hp = Hout + rr * ldh + (size_t)by * 256 + wn * 64 + (l & 15);
#pragma unroll
        for (int n = 0; n < 4; ++n) hp[n * 16] = (_Float16)gelu_fast(acc[m][n][j]);
      }
    }
  } else {
    _Float16* Yz = Yq + (size_t)bz * yzstride;
#pragma unroll
    for (int m = 0; m < 8; ++m) {
#pragma unroll
      for (int j = 0; j < 4; ++j) {
        size_t rr = (size_t)bx * 256 + wm * 128 + m * 16 + (l >> 4) * 4 + j;
        _Float16* yp = Yz + rr * DDIM + (size_t)by * 256 + wn * 64 + (l & 15);
        if (accum) {
#pragma unroll
          for (int n = 0; n < 4; ++n)
            yp[n * 16] = (_Float16)((float)yp[n * 16] + acc[m][n][j]);
        } else {
#pragma unroll
          for (int n = 0; n < 4; ++n) yp[n * 16] = (_Float16)acc[m][n][j];
        }
      }
    }
  }
}

// ---- combine: out[t] = sum_k ( w0*Yq[k][pos0] + w1*Yq[k][pos1] ) -----------
__global__ __launch_bounds__(128) void combine_kernel(
    const _Float16* __restrict__ Yq, int KQ, size_t yz,
    const int* __restrict__ inv_pos, const float* __restrict__ tok_w,
    float* __restrict__ out) {
  int t = blockIdx.x, l = threadIdx.x;
  int p0 = inv_pos[2 * t], p1 = inv_pos[2 * t + 1];
  float w0 = tok_w[2 * t], w1 = tok_w[2 * t + 1];
  float s[8] = {0, 0, 0, 0, 0, 0, 0, 0};
  for (int k = 0; k < KQ; ++k) {
    half8 h0 = *(const half8*)(Yq + k * yz + (size_t)p0 * DDIM + l * 8);
    half8 h1 = *(const half8*)(Yq + k * yz + (size_t)p1 * DDIM + l * 8);
#pragma unroll
    for (int j = 0; j < 8; ++j) s[j] += w0 * (float)h0[j] + w1 * (float)h1[j];
  }
  float4* o = (float4*)(out + (size_t)t * DDIM) + l * 2;
  o[0] = make_float4(s[0], s[1], s[2], s[3]);
  o[1] = make_float4(s[4], s[5], s[6], s[7]);
}

// ---------------- launch -----------------------------------------------------
extern "C" void kernel_launch(void* const* d_in, const int* in_sizes, int n_in,
                              void* d_out, int out_size, void* d_ws, size_t ws_size,
                              hipStream_t stream) {
  const float* x = (const float*)d_in[0];
  const float* rw = (const float*)d_in[1];
  const float* w1 = (const float*)d_in[2];
  const float* w2 = (const float*)d_in[3];
  float* out = (float*)d_out;

  char* base = (char*)d_ws;
  size_t off = 0;
  auto alloc = [&](size_t bytes) {
    void* p = base + off;
    off += (bytes + 255) & ~(size_t)255;
    return p;
  };
  const size_t SZ_W = (size_t)NEXP * FDIM * DDIM * 2;   // 64 MB each
  const size_t SZ_XG = (size_t)MAX_ROWS * DDIM * 2;     // ~37.8 MB
  const size_t SZ_YZ = (size_t)MAX_ROWS * DDIM * 2;     // per K-slab (fp16)

  // small buffers first (survive any aliasing)
  int* row_map = (int*)alloc(MAX_ROWS * 4);
  int* inv_pos = (int*)alloc(N_TOK * 2 * 4);
  int* tok_e = (int*)alloc(N_TOK * 2 * 4);
  float* tok_w = (float*)alloc(N_TOK * 2 * 4);
  int* meta = (int*)alloc(1024);
  _Float16* w2t = (_Float16*)alloc(SZ_W);
  size_t head = off;

  // Ladder: prefer NC=1/KQ=4. Layouts:
  //  plain:  head | H(151) | w1t | Xg | Yq(4 slabs)          need ~467MB
  //  alias:  head | H(151) | w1t | Xg | pad  (Yq = w1t..end) need ~367MB
  //  NC=2/KQ=2, NC=4/KQ=1: plain, smaller H/Yq.
  int NC = 1, KQ = 4;
  _Float16 *w1t, *Xg, *H, *Yq;
  size_t hsz1 = (size_t)MAX_ROWS * FDIM * 2;
  if (head + hsz1 + SZ_W + SZ_XG + 4 * SZ_YZ <= ws_size) {
    H = (_Float16*)alloc(hsz1);
    w1t = (_Float16*)alloc(SZ_W);
    Xg = (_Float16*)alloc(SZ_XG);
    Yq = (_Float16*)alloc(4 * SZ_YZ);
  } else if (head + hsz1 + SZ_W + SZ_XG <= ws_size &&
             head + hsz1 + 4 * SZ_YZ <= ws_size) {
    // alias: Yq overlays w1t+Xg+tail (w1t/Xg dead before GEMM2 at NC=1)
    H = (_Float16*)alloc(hsz1);
    w1t = (_Float16*)alloc(SZ_W);
    Xg = (_Float16*)alloc(SZ_XG);
    Yq = w1t;
  } else {
    NC = (head + (size_t)MAX_ROWS * (FDIM / 2) * 2 + SZ_W + SZ_XG + 2 * SZ_YZ <= ws_size) ? 2 : 4;
    KQ = 4 / NC;
    H = (_Float16*)alloc((size_t)MAX_ROWS * (FDIM / NC) * 2);
    w1t = (_Float16*)alloc(SZ_W);
    Xg = (_Float16*)alloc(SZ_XG);
    Yq = (_Float16*)alloc((size_t)KQ * SZ_YZ);
  }
  int Fc = FDIM / NC;

  hipMemsetAsync(meta, 0, 64, stream);                  // counts + fill
  hipMemsetAsync(row_map, 0xFF, MAX_ROWS * 4, stream);  // -1 sentinels

  conv_transpose<<<dim3(FDIM / 64, DDIM / 64, NEXP), 256, 0, stream>>>(w1, w1t, DDIM, FDIM);
  conv_transpose<<<dim3(DDIM / 64, FDIM / 64, NEXP), 256, 0, stream>>>(w2, w2t, FDIM, DDIM);
  router_kernel<<<N_TOK / 4, 256, 0, stream>>>(x, rw, tok_e, tok_w, meta);
  offsets_kernel<<<1, 64, 0, stream>>>(meta);
  gather_kernel<<<N_TOK * 2 / 256, 256, 0, stream>>>(tok_e, meta, row_map, inv_pos);
  xg_fill_kernel<<<MAX_ROWS, 128, 0, stream>>>(x, row_map, Xg);

  const int* be = meta + 32;
  size_t kqk = (size_t)Fc / KQ;   // K elems per K-quarter of GEMM2
  int nt2 = (int)(kqk / 64);      // 16 (NC1), 16 (NC2/KQ2), 16 (NC4/KQ1)
  for (int cc = 0; cc < NC; ++cc) {
    // GEMM1: Xg[M,1024] x w1t[e][Fc,1024]^T -> gelu -> H[M,Fc]
    gemmG<0><<<dim3(MAXB1 * (Fc / 256)), 512, 0, stream>>>(
        Xg, w1t + (size_t)cc * Fc * DDIM, be, MAXB1,
        (size_t)DDIM, (size_t)DDIM, DDIM / 64, (long long)FDIM * DDIM, 0,
        H, Fc, nullptr, 0, 0);
    // GEMM2: H[M,Fc] x w2t[e][1024,F(slice cc)]^T, K split KQ ways -> Yq
    gemmG<1><<<dim3(MAXB1 * 4 * KQ), 512, 0, stream>>>(
        H, w2t + (size_t)cc * Fc, be, MAXB1,
        (size_t)Fc, (size_t)FDIM, nt2, (long long)DDIM * FDIM, kqk,
        nullptr, 0, Yq, SZ_YZ / 2, cc > 0);
  }
  combine_kernel<<<N_TOK, 128, 0, stream>>>(Yq, KQ, SZ_YZ / 2, inv_pos, tok_w, out);
}

// Round 10
// 775.464 us; speedup vs baseline: 1.0382x; 1.0010x over previous
//
#include <hip/hip_runtime.h>
#include <stdint.h>

#define N_TOK 8192
#define DDIM 1024
#define FDIM 4096
#define NEXP 8
#define MAXB1 72                 // 256-row blocks: 16384 + 8*255 padded -> 72
#define MAX_ROWS (MAXB1 * 256)   // 18432

typedef _Float16 half8 __attribute__((ext_vector_type(8)));
typedef float floatx4 __attribute__((ext_vector_type(4)));

#define VMCNT(n) asm volatile("s_waitcnt vmcnt(" #n ")" ::: "memory")
#define LGKM0 asm volatile("s_waitcnt lgkmcnt(0)" ::: "memory")
#define MFMA16(a, b, c) __builtin_amdgcn_mfma_f32_16x16x32_f16(a, b, c, 0, 0, 0)

__device__ __forceinline__ void gload_lds16(const void* g, void* l) {
  __builtin_amdgcn_global_load_lds(
      (const __attribute__((address_space(1))) unsigned int*)(uintptr_t)g,
      (__attribute__((address_space(3))) unsigned int*)(uint32_t)(uintptr_t)l,
      16, 0, 0);
}

// fast exact-enough gelu: tanh form, max |dev| vs erf-gelu ~1e-3
__device__ __forceinline__ float gelu_fast(float v) {
  float u = v * (0.7978845608f + 0.0356774081f * v * v);
  float ev = __expf(2.f * u);
  float th = 1.f - 2.f / (ev + 1.f);  // tanh(u), safe at +/-inf
  return 0.5f * v * (1.f + th);
}

// ---- convert+transpose: fp32 src[R][C] -> fp16 dst[C][R], 64x64 tiles ------
__global__ __launch_bounds__(256) void conv_transpose(
    const float* __restrict__ src, _Float16* __restrict__ dst, int R, int C) {
  __shared__ float t[64][65];
  int e = blockIdx.z;
  const float* s = src + (size_t)e * R * C;
  _Float16* d = dst + (size_t)e * R * C;
  int c0 = blockIdx.x * 64, r0 = blockIdx.y * 64;
  int tid = threadIdx.x;
  int rl = tid >> 4, c4 = (tid & 15) * 4;
#pragma unroll
  for (int i = 0; i < 4; ++i) {
    float4 v = *(const float4*)(s + (size_t)(r0 + rl + i * 16) * C + c0 + c4);
    *(float4*)&t[rl + i * 16][c4] = v;
  }
  __syncthreads();
  int dr = tid >> 2, cc0 = (tid & 3) * 16;  // dst row = src col
#pragma unroll
  for (int h = 0; h < 2; ++h) {
    half8 o;
#pragma unroll
    for (int k = 0; k < 8; ++k) o[k] = (_Float16)t[cc0 + h * 8 + k][dr];
    *(half8*)(d + (size_t)(c0 + dr) * R + r0 + cc0 + h * 8) = o;
  }
}

// ---------------- router: logits, top-2, softmax(fp32), counts --------------
__global__ __launch_bounds__(256) void router_kernel(
    const float* __restrict__ x, const float* __restrict__ rw,
    int* __restrict__ tok_e, float* __restrict__ tok_w, int* __restrict__ meta) {
  __shared__ float srw[NEXP * DDIM];
  int tid = threadIdx.x;
  const float4* rw4 = (const float4*)rw;
  float4* srw4 = (float4*)srw;
#pragma unroll
  for (int i = 0; i < 8; ++i) srw4[tid + i * 256] = rw4[tid + i * 256];
  __syncthreads();

  int wv = tid >> 6, l = tid & 63;
  int t = blockIdx.x * 4 + wv;
  const float4* xr = (const float4*)(x + (size_t)t * DDIM + l * 16);
  float4 xv[4];
#pragma unroll
  for (int i = 0; i < 4; ++i) xv[i] = xr[i];

  float logit[NEXP];
#pragma unroll
  for (int e = 0; e < NEXP; ++e) {
    const float4* wr4 = (const float4*)(srw + e * DDIM + l * 16);
    float acc = 0.f;
#pragma unroll
    for (int i = 0; i < 4; ++i) {
      float4 w4 = wr4[i];
      acc += xv[i].x * w4.x + xv[i].y * w4.y + xv[i].z * w4.z + xv[i].w * w4.w;
    }
#pragma unroll
    for (int off = 32; off > 0; off >>= 1) acc += __shfl_xor(acc, off);
    logit[e] = acc;
  }
  if (l == 0) {
    int i1 = 0;
    float v1 = logit[0];
#pragma unroll
    for (int e = 1; e < NEXP; ++e)
      if (logit[e] > v1) { v1 = logit[e]; i1 = e; }
    int i2 = -1;
    float v2 = -1e30f;
#pragma unroll
    for (int e = 0; e < NEXP; ++e)
      if (e != i1 && logit[e] > v2) { v2 = logit[e]; i2 = e; }
    float ex = expf(v2 - v1);  // v2 <= v1
    float denom = 1.f + ex;
    tok_e[2 * t] = i1;
    tok_e[2 * t + 1] = i2;
    tok_w[2 * t] = 1.f / denom;
    tok_w[2 * t + 1] = ex / denom;
    atomicAdd(&meta[i1], 1);
    atomicAdd(&meta[i2], 1);
  }
}

// ---- offsets: 256-padded segments + block->expert table --------------------
__global__ void offsets_kernel(int* meta) {
  __shared__ int seg[NEXP + 1];
  int l = threadIdx.x;
  if (l == 0) {
    int s = 0;
    for (int e = 0; e < NEXP; ++e) {
      seg[e] = s;
      meta[16 + e] = s;
      meta[8 + e] = s;  // fill cursor starts at segment base
      s += (meta[e] + 255) & ~255;
    }
    seg[NEXP] = s;
    meta[16 + NEXP] = s;
  }
  __syncthreads();
  for (int b = l; b < MAXB1; b += 64) {
    int row = b * 256, ee = -1;
#pragma unroll
    for (int e = 0; e < NEXP; ++e)
      if (row >= seg[e] && row < seg[e + 1]) ee = e;
    meta[32 + b] = ee;
  }
}

// ---- gather: pair -> slot; also inverse map pair -> position ---------------
__global__ void gather_kernel(const int* __restrict__ tok_e, int* meta,
                              int* __restrict__ row_map, int* __restrict__ inv_pos) {
  int p = blockIdx.x * 256 + threadIdx.x;  // 0..16383
  int e = tok_e[p];
  int pos = atomicAdd(&meta[8 + e], 1);
  row_map[pos] = p >> 1;
  inv_pos[p] = pos;
}

// ---- Xg fill: gather x rows as fp16 (zeros for pads) -----------------------
__global__ void xg_fill_kernel(const float* __restrict__ x,
                               const int* __restrict__ row_map,
                               _Float16* __restrict__ Xg) {
  int r = blockIdx.x, t = threadIdx.x;
  int n = row_map[r];
  half8 h = {0, 0, 0, 0, 0, 0, 0, 0};
  if (n >= 0) {
    const float4* s = (const float4*)(x + (size_t)n * DDIM + t * 8);
    float4 a = s[0], b = s[1];
    h[0] = (_Float16)a.x; h[1] = (_Float16)a.y;
    h[2] = (_Float16)a.z; h[3] = (_Float16)a.w;
    h[4] = (_Float16)b.x; h[5] = (_Float16)b.y;
    h[6] = (_Float16)b.z; h[7] = (_Float16)b.w;
  }
  *(half8*)(Xg + (size_t)r * DDIM + t * 8) = h;
}

// ---- grouped GEMM, 256x256x64, 8 waves, 4-phase counted-vmcnt pipeline -----
// LDA/LDB compile-time (powers of 2): stage/read addresses fold to hoisted
// per-thread bases + scalar per-tile offsets (kills 64-bit VALU addr chains).
// Supergroups: 4 bx x 4 c per group, groups XCD-swizzled bijectively.
// Tail: guarded stages (no wrap) + VMCNT(0) at penultimate tile's p3.
// Steady-state coverage (per-wave queue, 8 issues/tile, drain-to-6 each p3):
//   entering tile t: Q = [B(t+1)c01, B(t+1)c23, A(t+1)c02]; p3's VMCNT(6)
//   drains Q + A(t+1)c13 -> all of tile t+1 confirmed before its phase 0.
template <int EPI, int LDA, int LDB>
__global__ __launch_bounds__(512, 2) void gemmG(
    const _Float16* __restrict__ A, const _Float16* __restrict__ Bbase,
    const int* __restrict__ be, int nbx, int nt, long long b_estride,
    size_t kqk, _Float16* __restrict__ Hout, int ldh,
    _Float16* __restrict__ Yq, size_t yzstride, int accum) {
  // ---- supergroup mapping ----
  int wg = blockIdx.x;
  int g = wg >> 4, r = wg & 15;
  int ngr = (int)gridDim.x >> 4;
  int q = ngr >> 3, r8 = ngr & 7, xcg = g & 7, og = g >> 3;
  int gs = (xcg < r8 ? xcg * (q + 1) : r8 * (q + 1) + (xcg - r8) * q) + og;
  int ngx = nbx >> 2;
  int gx = gs % ngx, gy = gs / ngx;
  int bx = gx * 4 + (r & 3);
  int c = gy * 4 + (r >> 2);
  int e = be[bx];
  if (e < 0) return;
  int by, bz;
  if (EPI == 1) { by = c & 3; bz = c >> 2; } else { by = c; bz = 0; }

  __shared__ __align__(16) _Float16 sA[2][256 * 64];
  __shared__ __align__(16) _Float16 sB[2][256 * 64];

  int tid = threadIdx.x, l = tid & 63, wid = tid >> 6;
  int wm = wid >> 2, wn = wid & 3;
  int rbA = wm * 128 + (l & 15);
  int cbB = wn * 64 + (l & 15);
  int sw = (l & 7) << 4;
  int ko0 = (((l >> 4) << 4) ^ sw) >> 1;         // fp16 elems, kk=0
  int ko1 = ((64 + ((l >> 4) << 4)) ^ sw) >> 1;  // kk=1
  int srow = tid >> 3;                           // 0..63 within a 64-row chunk
  int scol = ((((tid & 7) << 4) ^ ((srow & 7) << 4)) >> 1);

  // hoisted per-thread stage bases (compile-time strides -> shifts, LICM'd)
  const _Float16* Ab = A + (size_t)bx * 256 * LDA + (size_t)bz * kqk +
                       (size_t)srow * LDA + scol;
  const _Float16* Bb = Bbase + (size_t)e * b_estride + (size_t)by * 256 * LDB +
                       (size_t)bz * kqk + (size_t)srow * LDB + scol;

  floatx4 acc[8][4] = {};

  auto stA = [&](int t, int half) {  // A chunks {half, half+2} of tile t
    const _Float16* src = Ab + (size_t)t * 64;
    _Float16* dst = sA[t & 1];
    gload_lds16(src + half * (64 * LDA), dst + half * 4096 + tid * 8);
    gload_lds16(src + (half + 2) * (64 * LDA), dst + (half + 2) * 4096 + tid * 8);
  };
  auto stB = [&](int t, int c0) {  // B chunks {c0, c0+1} of tile t
    const _Float16* src = Bb + (size_t)t * 64;
    _Float16* dst = sB[t & 1];
    gload_lds16(src + c0 * (64 * LDB), dst + c0 * 4096 + tid * 8);
    gload_lds16(src + (c0 + 1) * (64 * LDB), dst + (c0 + 1) * 4096 + tid * 8);
  };

  // prologue: B(0), A(0), B(1), A(1)-half0  (14 loads; drain oldest 8)
  stB(0, 0); stB(0, 2);
  stA(0, 0);
  stA(0, 1);
  stB(1, 0); stB(1, 2);
  stA(1, 0);
  VMCNT(6);
  __builtin_amdgcn_s_barrier();

  for (int t = 0; t < nt; ++t) {
    const _Float16* sAb = sA[t & 1];
    const _Float16* sBb = sB[t & 1];
    half8 bf[4][2], af[4];

    // ---- phase 0: read B(all)+A(mh0,kk0); stage a1(t+1) ----
#pragma unroll
    for (int n = 0; n < 4; ++n) {
      bf[n][0] = *(const half8*)&sBb[(cbB + n * 16) * 64 + ko0];
      bf[n][1] = *(const half8*)&sBb[(cbB + n * 16) * 64 + ko1];
    }
#pragma unroll
    for (int m = 0; m < 4; ++m) af[m] = *(const half8*)&sAb[(rbA + m * 16) * 64 + ko0];
    if (t + 1 < nt) stA(t + 1, 1);
    __builtin_amdgcn_s_barrier();
    LGKM0; __builtin_amdgcn_sched_barrier(0);
    __builtin_amdgcn_s_setprio(1);
#pragma unroll
    for (int m = 0; m < 4; ++m)
#pragma unroll
      for (int n = 0; n < 4; ++n) acc[m][n] = MFMA16(af[m], bf[n][0], acc[m][n]);
    __builtin_amdgcn_s_setprio(0);
    __builtin_amdgcn_s_barrier();
    // ---- phase 1: read A(mh0,kk1); stage B(t+2)[0,1] ----
#pragma unroll
    for (int m = 0; m < 4; ++m) af[m] = *(const half8*)&sAb[(rbA + m * 16) * 64 + ko1];
    if (t + 2 < nt) stB(t + 2, 0);
    VMCNT(10);
    __builtin_amdgcn_s_barrier();
    LGKM0; __builtin_amdgcn_sched_barrier(0);
    __builtin_amdgcn_s_setprio(1);
#pragma unroll
    for (int m = 0; m < 4; ++m)
#pragma unroll
      for (int n = 0; n < 4; ++n) acc[m][n] = MFMA16(af[m], bf[n][1], acc[m][n]);
    __builtin_amdgcn_s_setprio(0);
    __builtin_amdgcn_s_barrier();
    // ---- phase 2: read A(mh1,kk0); stage B(t+2)[2,3] ----
#pragma unroll
    for (int m = 0; m < 4; ++m) af[m] = *(const half8*)&sAb[(rbA + 64 + m * 16) * 64 + ko0];
    if (t + 2 < nt) stB(t + 2, 2);
    __builtin_amdgcn_s_barrier();
    LGKM0; __builtin_amdgcn_sched_barrier(0);
    __builtin_amdgcn_s_setprio(1);
#pragma unroll
    for (int m = 0; m < 4; ++m)
#pragma unroll
      for (int n = 0; n < 4; ++n) acc[4 + m][n] = MFMA16(af[m], bf[n][0], acc[4 + m][n]);
    __builtin_amdgcn_s_setprio(0);
    __builtin_amdgcn_s_barrier();
    // ---- phase 3: read A(mh1,kk1); stage a0(t+2); VMCNT(6)/(0 at tail) ----
#pragma unroll
    for (int m = 0; m < 4; ++m) af[m] = *(const half8*)&sAb[(rbA + 64 + m * 16) * 64 + ko1];
    if (t + 2 < nt) {
      stA(t + 2, 0);
      VMCNT(6);
    } else {
      VMCNT(0);  // tail: confirm everything (incl. a1(t+1) staged at p0)
    }
    __builtin_amdgcn_s_barrier();
    LGKM0; __builtin_amdgcn_sched_barrier(0);
    __builtin_amdgcn_s_setprio(1);
#pragma unroll
    for (int m = 0; m < 4; ++m)
#pragma unroll
      for (int n = 0; n < 4; ++n) acc[4 + m][n] = MFMA16(af[m], bf[n][1], acc[4 + m][n]);
    __builtin_amdgcn_s_setprio(0);
    __builtin_amdgcn_s_barrier();
  }

  if (EPI == 0) {
#pragma unroll
    for (int m = 0; m < 8; ++m) {
#pragma unroll
      for (int j = 0; j < 4; ++j) {
        size_t rr = (size_t)bx * 256 + wm * 128 + m * 16 + (l >> 4) * 4 + j;
        _Float16* hp = Hout + rr * ldh + (size_t)by * 256 + wn * 64 + (l & 15);
#pragma unroll
        for (int n = 0; n < 4; ++n) hp[n * 16] = (_Float16)gelu_fast(acc[m][n][j]);
      }
    }
  } else {
    _Float16* Yz = Yq + (size_t)bz * yzstride;
#pragma unroll
    for (int m = 0; m < 8; ++m) {
#pragma unroll
      for (int j = 0; j < 4; ++j) {
        size_t rr = (size_t)bx * 256 + wm * 128 + m * 16 + (l >> 4) * 4 + j;
        _Float16* yp = Yz + rr * DDIM + (size_t)by * 256 + wn * 64 + (l & 15);
        if (accum) {
#pragma unroll
          for (int n = 0; n < 4; ++n)
            yp[n * 16] = (_Float16)((float)yp[n * 16] + acc[m][n][j]);
        } else {
#pragma unroll
          for (int n = 0; n < 4; ++n) yp[n * 16] = (_Float16)acc[m][n][j];
        }
      }
    }
  }
}

// ---- combine: out[t] = sum_k ( w0*Yq[k][pos0] + w1*Yq[k][pos1] ) -----------
__global__ __launch_bounds__(128) void combine_kernel(
    const _Float16* __restrict__ Yq, int KQ, size_t yz,
    const int* __restrict__ inv_pos, const float* __restrict__ tok_w,
    float* __restrict__ out) {
  int t = blockIdx.x, l = threadIdx.x;
  int p0 = inv_pos[2 * t], p1 = inv_pos[2 * t + 1];
  float w0 = tok_w[2 * t], w1 = tok_w[2 * t + 1];
  float s[8] = {0, 0, 0, 0, 0, 0, 0, 0};
  for (int k = 0; k < KQ; ++k) {
    half8 h0 = *(const half8*)(Yq + k * yz + (size_t)p0 * DDIM + l * 8);
    half8 h1 = *(const half8*)(Yq + k * yz + (size_t)p1 * DDIM + l * 8);
#pragma unroll
    for (int j = 0; j < 8; ++j) s[j] += w0 * (float)h0[j] + w1 * (float)h1[j];
  }
  float4* o = (float4*)(out + (size_t)t * DDIM) + l * 2;
  o[0] = make_float4(s[0], s[1], s[2], s[3]);
  o[1] = make_float4(s[4], s[5], s[6], s[7]);
}

// ---------------- launch -----------------------------------------------------
extern "C" void kernel_launch(void* const* d_in, const int* in_sizes, int n_in,
                              void* d_out, int out_size, void* d_ws, size_t ws_size,
                              hipStream_t stream) {
  const float* x = (const float*)d_in[0];
  const float* rw = (const float*)d_in[1];
  const float* w1 = (const float*)d_in[2];
  const float* w2 = (const float*)d_in[3];
  float* out = (float*)d_out;

  char* base = (char*)d_ws;
  size_t off = 0;
  auto alloc = [&](size_t bytes) {
    void* p = base + off;
    off += (bytes + 255) & ~(size_t)255;
    return p;
  };
  const size_t SZ_W = (size_t)NEXP * FDIM * DDIM * 2;   // 64 MB each
  const size_t SZ_XG = (size_t)MAX_ROWS * DDIM * 2;     // ~37.8 MB
  const size_t SZ_YZ = (size_t)MAX_ROWS * DDIM * 2;     // per K-slab (fp16)

  // small buffers first (survive any aliasing)
  int* row_map = (int*)alloc(MAX_ROWS * 4);
  int* inv_pos = (int*)alloc(N_TOK * 2 * 4);
  int* tok_e = (int*)alloc(N_TOK * 2 * 4);
  float* tok_w = (float*)alloc(N_TOK * 2 * 4);
  int* meta = (int*)alloc(1024);
  _Float16* w2t = (_Float16*)alloc(SZ_W);
  size_t head = off;

  int NC = 1, KQ = 4;
  _Float16 *w1t, *Xg, *H, *Yq;
  size_t hsz1 = (size_t)MAX_ROWS * FDIM * 2;
  if (head + hsz1 + SZ_W + SZ_XG + 4 * SZ_YZ <= ws_size) {
    H = (_Float16*)alloc(hsz1);
    w1t = (_Float16*)alloc(SZ_W);
    Xg = (_Float16*)alloc(SZ_XG);
    Yq = (_Float16*)alloc(4 * SZ_YZ);
  } else if (head + hsz1 + SZ_W + SZ_XG <= ws_size &&
             head + hsz1 + 4 * SZ_YZ <= ws_size) {
    // alias: Yq overlays w1t+Xg+tail (w1t/Xg dead before GEMM2 at NC=1)
    H = (_Float16*)alloc(hsz1);
    w1t = (_Float16*)alloc(SZ_W);
    Xg = (_Float16*)alloc(SZ_XG);
    Yq = w1t;
  } else {
    NC = (head + (size_t)MAX_ROWS * (FDIM / 2) * 2 + SZ_W + SZ_XG + 2 * SZ_YZ <= ws_size) ? 2 : 4;
    KQ = 4 / NC;
    H = (_Float16*)alloc((size_t)MAX_ROWS * (FDIM / NC) * 2);
    w1t = (_Float16*)alloc(SZ_W);
    Xg = (_Float16*)alloc(SZ_XG);
    Yq = (_Float16*)alloc((size_t)KQ * SZ_YZ);
  }
  int Fc = FDIM / NC;

  hipMemsetAsync(meta, 0, 64, stream);                  // counts + fill
  hipMemsetAsync(row_map, 0xFF, MAX_ROWS * 4, stream);  // -1 sentinels

  conv_transpose<<<dim3(FDIM / 64, DDIM / 64, NEXP), 256, 0, stream>>>(w1, w1t, DDIM, FDIM);
  conv_transpose<<<dim3(DDIM / 64, FDIM / 64, NEXP), 256, 0, stream>>>(w2, w2t, FDIM, DDIM);
  router_kernel<<<N_TOK / 4, 256, 0, stream>>>(x, rw, tok_e, tok_w, meta);
  offsets_kernel<<<1, 64, 0, stream>>>(meta);
  gather_kernel<<<N_TOK * 2 / 256, 256, 0, stream>>>(tok_e, meta, row_map, inv_pos);
  xg_fill_kernel<<<MAX_ROWS, 128, 0, stream>>>(x, row_map, Xg);

  const int* be = meta + 32;
  size_t kqk = (size_t)Fc / KQ;   // K elems per K-slab of GEMM2
  int nt2 = (int)(kqk / 64);      // 16 in all ladder configs
  for (int cc = 0; cc < NC; ++cc) {
    // GEMM1: Xg[M,1024] x w1t[e][Fc,1024]^T -> gelu -> H[M,Fc]
    gemmG<0, DDIM, DDIM><<<dim3(MAXB1 * (Fc / 256)), 512, 0, stream>>>(
        Xg, w1t + (size_t)cc * Fc * DDIM, be, MAXB1,
        DDIM / 64, (long long)FDIM * DDIM, 0, H, Fc, nullptr, 0, 0);
    // GEMM2: H[M,Fc] x w2t[e][1024,F(slice cc)]^T, K split KQ ways -> Yq
    if (NC == 1)
      gemmG<1, 4096, FDIM><<<dim3(MAXB1 * 4 * KQ), 512, 0, stream>>>(
          H, w2t + (size_t)cc * Fc, be, MAXB1, nt2,
          (long long)DDIM * FDIM, kqk, nullptr, 0, Yq, SZ_YZ / 2, cc > 0);
    else if (NC == 2)
      gemmG<1, 2048, FDIM><<<dim3(MAXB1 * 4 * KQ), 512, 0, stream>>>(
          H, w2t + (size_t)cc * Fc, be, MAXB1, nt2,
          (long long)DDIM * FDIM, kqk, nullptr, 0, Yq, SZ_YZ / 2, cc > 0);
    else
      gemmG<1, 1024, FDIM><<<dim3(MAXB1 * 4 * KQ), 512, 0, stream>>>(
          H, w2t + (size_t)cc * Fc, be, MAXB1, nt2,
          (long long)DDIM * FDIM, kqk, nullptr, 0, Yq, SZ_YZ / 2, cc > 0);
  }
  combine_kernel<<<N_TOK, 128, 0, stream>>>(Yq, KQ, SZ_YZ / 2, inv_pos, tok_w, out);
}

// Round 11
// 775.352 us; speedup vs baseline: 1.0383x; 1.0001x over previous
//
#include <hip/hip_runtime.h>
#include <stdint.h>

#define N_TOK 8192
#define DDIM 1024
#define FDIM 4096
#define NEXP 8
#define MAXB1 72                 // 256-row blocks: 16384 + 8*255 padded -> 72
#define MAX_ROWS (MAXB1 * 256)   // 18432

typedef _Float16 half8 __attribute__((ext_vector_type(8)));
typedef float floatx4 __attribute__((ext_vector_type(4)));

#define VMCNT(n) asm volatile("s_waitcnt vmcnt(" #n ")" ::: "memory")
#define LGKM0 asm volatile("s_waitcnt lgkmcnt(0)" ::: "memory")
#define MFMA16(a, b, c) __builtin_amdgcn_mfma_f32_16x16x32_f16(a, b, c, 0, 0, 0)

__device__ __forceinline__ void gload_lds16(const void* g, void* l) {
  __builtin_amdgcn_global_load_lds(
      (const __attribute__((address_space(1))) unsigned int*)(uintptr_t)g,
      (__attribute__((address_space(3))) unsigned int*)(uint32_t)(uintptr_t)l,
      16, 0, 0);
}

// fast exact-enough gelu: tanh form, max |dev| vs erf-gelu ~1e-3
__device__ __forceinline__ float gelu_fast(float v) {
  float u = v * (0.7978845608f + 0.0356774081f * v * v);
  float ev = __expf(2.f * u);
  float th = 1.f - 2.f / (ev + 1.f);  // tanh(u), safe at +/-inf
  return 0.5f * v * (1.f + th);
}

// ---- convert+transpose: fp32 src[R][C] -> fp16 dst[C][R], 64x64 tiles ------
__global__ __launch_bounds__(256) void conv_transpose(
    const float* __restrict__ src, _Float16* __restrict__ dst, int R, int C) {
  __shared__ float t[64][65];
  int e = blockIdx.z;
  const float* s = src + (size_t)e * R * C;
  _Float16* d = dst + (size_t)e * R * C;
  int c0 = blockIdx.x * 64, r0 = blockIdx.y * 64;
  int tid = threadIdx.x;
  int rl = tid >> 4, c4 = (tid & 15) * 4;
#pragma unroll
  for (int i = 0; i < 4; ++i) {
    float4 v = *(const float4*)(s + (size_t)(r0 + rl + i * 16) * C + c0 + c4);
    *(float4*)&t[rl + i * 16][c4] = v;
  }
  __syncthreads();
  int dr = tid >> 2, cc0 = (tid & 3) * 16;  // dst row = src col
#pragma unroll
  for (int h = 0; h < 2; ++h) {
    half8 o;
#pragma unroll
    for (int k = 0; k < 8; ++k) o[k] = (_Float16)t[cc0 + h * 8 + k][dr];
    *(half8*)(d + (size_t)(c0 + dr) * R + r0 + cc0 + h * 8) = o;
  }
}

// ---------------- router: logits, top-2, softmax(fp32), counts --------------
__global__ __launch_bounds__(256) void router_kernel(
    const float* __restrict__ x, const float* __restrict__ rw,
    int* __restrict__ tok_e, float* __restrict__ tok_w, int* __restrict__ meta) {
  __shared__ float srw[NEXP * DDIM];
  int tid = threadIdx.x;
  const float4* rw4 = (const float4*)rw;
  float4* srw4 = (float4*)srw;
#pragma unroll
  for (int i = 0; i < 8; ++i) srw4[tid + i * 256] = rw4[tid + i * 256];
  __syncthreads();

  int wv = tid >> 6, l = tid & 63;
  int t = blockIdx.x * 4 + wv;
  const float4* xr = (const float4*)(x + (size_t)t * DDIM + l * 16);
  float4 xv[4];
#pragma unroll
  for (int i = 0; i < 4; ++i) xv[i] = xr[i];

  float logit[NEXP];
#pragma unroll
  for (int e = 0; e < NEXP; ++e) {
    const float4* wr4 = (const float4*)(srw + e * DDIM + l * 16);
    float acc = 0.f;
#pragma unroll
    for (int i = 0; i < 4; ++i) {
      float4 w4 = wr4[i];
      acc += xv[i].x * w4.x + xv[i].y * w4.y + xv[i].z * w4.z + xv[i].w * w4.w;
    }
#pragma unroll
    for (int off = 32; off > 0; off >>= 1) acc += __shfl_xor(acc, off);
    logit[e] = acc;
  }
  if (l == 0) {
    int i1 = 0;
    float v1 = logit[0];
#pragma unroll
    for (int e = 1; e < NEXP; ++e)
      if (logit[e] > v1) { v1 = logit[e]; i1 = e; }
    int i2 = -1;
    float v2 = -1e30f;
#pragma unroll
    for (int e = 0; e < NEXP; ++e)
      if (e != i1 && logit[e] > v2) { v2 = logit[e]; i2 = e; }
    float ex = expf(v2 - v1);  // v2 <= v1
    float denom = 1.f + ex;
    tok_e[2 * t] = i1;
    tok_e[2 * t + 1] = i2;
    tok_w[2 * t] = 1.f / denom;
    tok_w[2 * t + 1] = ex / denom;
    atomicAdd(&meta[i1], 1);
    atomicAdd(&meta[i2], 1);
  }
}

// ---- offsets: 256-padded segments + block->expert table --------------------
__global__ void offsets_kernel(int* meta) {
  __shared__ int seg[NEXP + 1];
  int l = threadIdx.x;
  if (l == 0) {
    int s = 0;
    for (int e = 0; e < NEXP; ++e) {
      seg[e] = s;
      meta[16 + e] = s;
      meta[8 + e] = s;  // fill cursor starts at segment base
      s += (meta[e] + 255) & ~255;
    }
    seg[NEXP] = s;
    meta[16 + NEXP] = s;
  }
  __syncthreads();
  for (int b = l; b < MAXB1; b += 64) {
    int row = b * 256, ee = -1;
#pragma unroll
    for (int e = 0; e < NEXP; ++e)
      if (row >= seg[e] && row < seg[e + 1]) ee = e;
    meta[32 + b] = ee;
  }
}

// ---- gather: pair -> slot; also inverse map pair -> position ---------------
__global__ void gather_kernel(const int* __restrict__ tok_e, int* meta,
                              int* __restrict__ row_map, int* __restrict__ inv_pos) {
  int p = blockIdx.x * 256 + threadIdx.x;  // 0..16383
  int e = tok_e[p];
  int pos = atomicAdd(&meta[8 + e], 1);
  row_map[pos] = p >> 1;
  inv_pos[p] = pos;
}

// ---- Xg fill: gather x rows as fp16 (zeros for pads) -----------------------
__global__ void xg_fill_kernel(const float* __restrict__ x,
                               const int* __restrict__ row_map,
                               _Float16* __restrict__ Xg) {
  int r = blockIdx.x, t = threadIdx.x;
  int n = row_map[r];
  half8 h = {0, 0, 0, 0, 0, 0, 0, 0};
  if (n >= 0) {
    const float4* s = (const float4*)(x + (size_t)n * DDIM + t * 8);
    float4 a = s[0], b = s[1];
    h[0] = (_Float16)a.x; h[1] = (_Float16)a.y;
    h[2] = (_Float16)a.z; h[3] = (_Float16)a.w;
    h[4] = (_Float16)b.x; h[5] = (_Float16)b.y;
    h[6] = (_Float16)b.z; h[7] = (_Float16)b.w;
  }
  *(half8*)(Xg + (size_t)r * DDIM + t * 8) = h;
}

// ---- grouped GEMM, 256x256x64, 8 waves, 4-phase counted-vmcnt pipeline -----
// XCD-PURE supergroups: dispatch round-robins consecutive blockIdx across the
// 8 XCDs (m09), so logical = (bid%8)*(nb/8) + bid/8 gives each XCD a
// CONTIGUOUS logical chunk (HK chiplet_transform). Groups of 16 logical ids
// (4 bx x 4 c) then sit entirely on one XCD: 2MB A + 2MB B = one 4MB L2.
// Consecutive co-resident groups share gy (gx-fastest) -> B-panels shared.
template <int EPI, int LDA, int LDB>
__global__ __launch_bounds__(512, 2) void gemmG(
    const _Float16* __restrict__ A, const _Float16* __restrict__ Bbase,
    const int* __restrict__ be, int nbx, int nt, long long b_estride,
    size_t kqk, _Float16* __restrict__ Hout, int ldh,
    _Float16* __restrict__ Yq, size_t yzstride, int accum) {
  // ---- XCD-pure supergroup mapping ----
  int bid = blockIdx.x, nb = gridDim.x;
  int logical = (bid & 7) * (nb >> 3) + (bid >> 3);  // nb % 8 == 0 always
  int g = logical >> 4, r = logical & 15;
  int ngx = nbx >> 2;
  int gx = g % ngx, gy = g / ngx;
  int bx = gx * 4 + (r & 3);
  int c = gy * 4 + (r >> 2);
  int e = be[bx];
  if (e < 0) return;
  int by, bz;
  if (EPI == 1) { by = c & 3; bz = c >> 2; } else { by = c; bz = 0; }

  __shared__ __align__(16) _Float16 sA[2][256 * 64];
  __shared__ __align__(16) _Float16 sB[2][256 * 64];

  int tid = threadIdx.x, l = tid & 63, wid = tid >> 6;
  int wm = wid >> 2, wn = wid & 3;
  int rbA = wm * 128 + (l & 15);
  int cbB = wn * 64 + (l & 15);
  int sw = (l & 7) << 4;
  int ko0 = (((l >> 4) << 4) ^ sw) >> 1;         // fp16 elems, kk=0
  int ko1 = ((64 + ((l >> 4) << 4)) ^ sw) >> 1;  // kk=1
  int srow = tid >> 3;                           // 0..63 within a 64-row chunk
  int scol = ((((tid & 7) << 4) ^ ((srow & 7) << 4)) >> 1);

  // hoisted per-thread stage bases (compile-time strides -> shifts, LICM'd)
  const _Float16* Ab = A + (size_t)bx * 256 * LDA + (size_t)bz * kqk +
                       (size_t)srow * LDA + scol;
  const _Float16* Bb = Bbase + (size_t)e * b_estride + (size_t)by * 256 * LDB +
                       (size_t)bz * kqk + (size_t)srow * LDB + scol;

  floatx4 acc[8][4] = {};

  auto stA = [&](int t, int half) {  // A chunks {half, half+2} of tile t
    const _Float16* src = Ab + (size_t)t * 64;
    _Float16* dst = sA[t & 1];
    gload_lds16(src + half * (64 * LDA), dst + half * 4096 + tid * 8);
    gload_lds16(src + (half + 2) * (64 * LDA), dst + (half + 2) * 4096 + tid * 8);
  };
  auto stB = [&](int t, int c0) {  // B chunks {c0, c0+1} of tile t
    const _Float16* src = Bb + (size_t)t * 64;
    _Float16* dst = sB[t & 1];
    gload_lds16(src + c0 * (64 * LDB), dst + c0 * 4096 + tid * 8);
    gload_lds16(src + (c0 + 1) * (64 * LDB), dst + (c0 + 1) * 4096 + tid * 8);
  };

  // prologue: B(0), A(0), B(1), A(1)-half0  (14 loads; drain oldest 8)
  stB(0, 0); stB(0, 2);
  stA(0, 0);
  stA(0, 1);
  stB(1, 0); stB(1, 2);
  stA(1, 0);
  VMCNT(6);
  __builtin_amdgcn_s_barrier();

  for (int t = 0; t < nt; ++t) {
    const _Float16* sAb = sA[t & 1];
    const _Float16* sBb = sB[t & 1];
    half8 bf[4][2], af[4];

    // ---- phase 0: read B(all)+A(mh0,kk0); stage a1(t+1) ----
#pragma unroll
    for (int n = 0; n < 4; ++n) {
      bf[n][0] = *(const half8*)&sBb[(cbB + n * 16) * 64 + ko0];
      bf[n][1] = *(const half8*)&sBb[(cbB + n * 16) * 64 + ko1];
    }
#pragma unroll
    for (int m = 0; m < 4; ++m) af[m] = *(const half8*)&sAb[(rbA + m * 16) * 64 + ko0];
    if (t + 1 < nt) stA(t + 1, 1);
    __builtin_amdgcn_s_barrier();
    LGKM0; __builtin_amdgcn_sched_barrier(0);
    __builtin_amdgcn_s_setprio(1);
#pragma unroll
    for (int m = 0; m < 4; ++m)
#pragma unroll
      for (int n = 0; n < 4; ++n) acc[m][n] = MFMA16(af[m], bf[n][0], acc[m][n]);
    __builtin_amdgcn_s_setprio(0);
    __builtin_amdgcn_s_barrier();
    // ---- phase 1: read A(mh0,kk1); stage B(t+2)[0,1] ----
#pragma unroll
    for (int m = 0; m < 4; ++m) af[m] = *(const half8*)&sAb[(rbA + m * 16) * 64 + ko1];
    if (t + 2 < nt) stB(t + 2, 0);
    VMCNT(10);
    __builtin_amdgcn_s_barrier();
    LGKM0; __builtin_amdgcn_sched_barrier(0);
    __builtin_amdgcn_s_setprio(1);
#pragma unroll
    for (int m = 0; m < 4; ++m)
#pragma unroll
      for (int n = 0; n < 4; ++n) acc[m][n] = MFMA16(af[m], bf[n][1], acc[m][n]);
    __builtin_amdgcn_s_setprio(0);
    __builtin_amdgcn_s_barrier();
    // ---- phase 2: read A(mh1,kk0); stage B(t+2)[2,3] ----
#pragma unroll
    for (int m = 0; m < 4; ++m) af[m] = *(const half8*)&sAb[(rbA + 64 + m * 16) * 64 + ko0];
    if (t + 2 < nt) stB(t + 2, 2);
    __builtin_amdgcn_s_barrier();
    LGKM0; __builtin_amdgcn_sched_barrier(0);
    __builtin_amdgcn_s_setprio(1);
#pragma unroll
    for (int m = 0; m < 4; ++m)
#pragma unroll
      for (int n = 0; n < 4; ++n) acc[4 + m][n] = MFMA16(af[m], bf[n][0], acc[4 + m][n]);
    __builtin_amdgcn_s_setprio(0);
    __builtin_amdgcn_s_barrier();
    // ---- phase 3: read A(mh1,kk1); stage a0(t+2); VMCNT(6)/(0 at tail) ----
#pragma unroll
    for (int m = 0; m < 4; ++m) af[m] = *(const half8*)&sAb[(rbA + 64 + m * 16) * 64 + ko1];
    if (t + 2 < nt) {
      stA(t + 2, 0);
      VMCNT(6);
    } else {
      VMCNT(0);  // tail: confirm everything (incl. a1(t+1) staged at p0)
    }
    __builtin_amdgcn_s_barrier();
    LGKM0; __builtin_amdgcn_sched_barrier(0);
    __builtin_amdgcn_s_setprio(1);
#pragma unroll
    for (int m = 0; m < 4; ++m)
#pragma unroll
      for (int n = 0; n < 4; ++n) acc[4 + m][n] = MFMA16(af[m], bf[n][1], acc[4 + m][n]);
    __builtin_amdgcn_s_setprio(0);
    __builtin_amdgcn_s_barrier();
  }

  if (EPI == 0) {
#pragma unroll
    for (int m = 0; m < 8; ++m) {
#pragma unroll
      for (int j = 0; j < 4; ++j) {
        size_t rr = (size_t)bx * 256 + wm * 128 + m * 16 + (l >> 4) * 4 + j;
        _Float16* hp = Hout + rr * ldh + (size_t)by * 256 + wn * 64 + (l & 15);
#pragma unroll
        for (int n = 0; n < 4; ++n) hp[n * 16] = (_Float16)gelu_fast(acc[m][n][j]);
      }
    }
  } else {
    _Float16* Yz = Yq + (size_t)bz * yzstride;
#pragma unroll
    for (int m = 0; m < 8; ++m) {
#pragma unroll
      for (int j = 0; j < 4; ++j) {
        size_t rr = (size_t)bx * 256 + wm * 128 + m * 16 + (l >> 4) * 4 + j;
        _Float16* yp = Yz + rr * DDIM + (size_t)by * 256 + wn * 64 + (l & 15);
        if (accum) {
#pragma unroll
          for (int n = 0; n < 4; ++n)
            yp[n * 16] = (_Float16)((float)yp[n * 16] + acc[m][n][j]);
        } else {
#pragma unroll
          for (int n = 0; n < 4; ++n) yp[n * 16] = (_Float16)acc[m][n][j];
        }
      }
    }
  }
}

// ---- combine: out[t] = sum_k ( w0*Yq[k][pos0] + w1*Yq[k][pos1] ) -----------
__global__ __launch_bounds__(128) void combine_kernel(
    const _Float16* __restrict__ Yq, int KQ, size_t yz,
    const int* __restrict__ inv_pos, const float* __restrict__ tok_w,
    float* __restrict__ out) {
  int t = blockIdx.x, l = threadIdx.x;
  int p0 = inv_pos[2 * t], p1 = inv_pos[2 * t + 1];
  float w0 = tok_w[2 * t], w1 = tok_w[2 * t + 1];
  float s[8] = {0, 0, 0, 0, 0, 0, 0, 0};
  for (int k = 0; k < KQ; ++k) {
    half8 h0 = *(const half8*)(Yq + k * yz + (size_t)p0 * DDIM + l * 8);
    half8 h1 = *(const half8*)(Yq + k * yz + (size_t)p1 * DDIM + l * 8);
#pragma unroll
    for (int j = 0; j < 8; ++j) s[j] += w0 * (float)h0[j] + w1 * (float)h1[j];
  }
  float4* o = (float4*)(out + (size_t)t * DDIM) + l * 2;
  o[0] = make_float4(s[0], s[1], s[2], s[3]);
  o[1] = make_float4(s[4], s[5], s[6], s[7]);
}

// ---------------- launch -----------------------------------------------------
extern "C" void kernel_launch(void* const* d_in, const int* in_sizes, int n_in,
                              void* d_out, int out_size, void* d_ws, size_t ws_size,
                              hipStream_t stream) {
  const float* x = (const float*)d_in[0];
  const float* rw = (const float*)d_in[1];
  const float* w1 = (const float*)d_in[2];
  const float* w2 = (const float*)d_in[3];
  float* out = (float*)d_out;

  char* base = (char*)d_ws;
  size_t off = 0;
  auto alloc = [&](size_t bytes) {
    void* p = base + off;
    off += (bytes + 255) & ~(size_t)255;
    return p;
  };
  const size_t SZ_W = (size_t)NEXP * FDIM * DDIM * 2;   // 64 MB each
  const size_t SZ_XG = (size_t)MAX_ROWS * DDIM * 2;     // ~37.8 MB
  const size_t SZ_YZ = (size_t)MAX_ROWS * DDIM * 2;     // per K-slab (fp16)

  // small buffers first (survive any aliasing)
  int* row_map = (int*)alloc(MAX_ROWS * 4);
  int* inv_pos = (int*)alloc(N_TOK * 2 * 4);
  int* tok_e = (int*)alloc(N_TOK * 2 * 4);
  float* tok_w = (float*)alloc(N_TOK * 2 * 4);
  int* meta = (int*)alloc(1024);
  _Float16* w2t = (_Float16*)alloc(SZ_W);
  size_t head = off;

  int NC = 1, KQ = 4;
  _Float16 *w1t, *Xg, *H, *Yq;
  size_t hsz1 = (size_t)MAX_ROWS * FDIM * 2;
  if (head + hsz1 + SZ_W + SZ_XG + 4 * SZ_YZ <= ws_size) {
    H = (_Float16*)alloc(hsz1);
    w1t = (_Float16*)alloc(SZ_W);
    Xg = (_Float16*)alloc(SZ_XG);
    Yq = (_Float16*)alloc(4 * SZ_YZ);
  } else if (head + hsz1 + SZ_W + SZ_XG <= ws_size &&
             head + hsz1 + 4 * SZ_YZ <= ws_size) {
    // alias: Yq overlays w1t+Xg+tail (w1t/Xg dead before GEMM2 at NC=1)
    H = (_Float16*)alloc(hsz1);
    w1t = (_Float16*)alloc(SZ_W);
    Xg = (_Float16*)alloc(SZ_XG);
    Yq = w1t;
  } else {
    NC = (head + (size_t)MAX_ROWS * (FDIM / 2) * 2 + SZ_W + SZ_XG + 2 * SZ_YZ <= ws_size) ? 2 : 4;
    KQ = 4 / NC;
    H = (_Float16*)alloc((size_t)MAX_ROWS * (FDIM / NC) * 2);
    w1t = (_Float16*)alloc(SZ_W);
    Xg = (_Float16*)alloc(SZ_XG);
    Yq = (_Float16*)alloc((size_t)KQ * SZ_YZ);
  }
  int Fc = FDIM / NC;

  hipMemsetAsync(meta, 0, 64, stream);                  // counts + fill
  hipMemsetAsync(row_map, 0xFF, MAX_ROWS * 4, stream);  // -1 sentinels

  conv_transpose<<<dim3(FDIM / 64, DDIM / 64, NEXP), 256, 0, stream>>>(w1, w1t, DDIM, FDIM);
  conv_transpose<<<dim3(DDIM / 64, FDIM / 64, NEXP), 256, 0, stream>>>(w2, w2t, FDIM, DDIM);
  router_kernel<<<N_TOK / 4, 256, 0, stream>>>(x, rw, tok_e, tok_w, meta);
  offsets_kernel<<<1, 64, 0, stream>>>(meta);
  gather_kernel<<<N_TOK * 2 / 256, 256, 0, stream>>>(tok_e, meta, row_map, inv_pos);
  xg_fill_kernel<<<MAX_ROWS, 128, 0, stream>>>(x, row_map, Xg);

  const int* be = meta + 32;
  size_t kqk = (size_t)Fc / KQ;   // K elems per K-slab of GEMM2
  int nt2 = (int)(kqk / 64);      // 16 in all ladder configs
  for (int cc = 0; cc < NC; ++cc) {
    // GEMM1: Xg[M,1024] x w1t[e][Fc,1024]^T -> gelu -> H[M,Fc]
    gemmG<0, DDIM, DDIM><<<dim3(MAXB1 * (Fc / 256)), 512, 0, stream>>>(
        Xg, w1t + (size_t)cc * Fc * DDIM, be, MAXB1,
        DDIM / 64, (long long)FDIM * DDIM, 0, H, Fc, nullptr, 0, 0);
    // GEMM2: H[M,Fc] x w2t[e][1024,F(slice cc)]^T, K split KQ ways -> Yq
    if (NC == 1)
      gemmG<1, 4096, FDIM><<<dim3(MAXB1 * 4 * KQ), 512, 0, stream>>>(
          H, w2t + (size_t)cc * Fc, be, MAXB1, nt2,
          (long long)DDIM * FDIM, kqk, nullptr, 0, Yq, SZ_YZ / 2, cc > 0);
    else if (NC == 2)
      gemmG<1, 2048, FDIM><<<dim3(MAXB1 * 4 * KQ), 512, 0, stream>>>(
          H, w2t + (size_t)cc * Fc, be, MAXB1, nt2,
          (long long)DDIM * FDIM, kqk, nullptr, 0, Yq, SZ_YZ / 2, cc > 0);
    else
      gemmG<1, 1024, FDIM><<<dim3(MAXB1 * 4 * KQ), 512, 0, stream>>>(
          H, w2t + (size_t)cc * Fc, be, MAXB1, nt2,
          (long long)DDIM * FDIM, kqk, nullptr, 0, Yq, SZ_YZ / 2, cc > 0);
  }
  combine_kernel<<<N_TOK, 128, 0, stream>>>(Yq, KQ, SZ_YZ / 2, inv_pos, tok_w, out);
}

// Round 12
// 569.594 us; speedup vs baseline: 1.4134x; 1.3612x over previous
//
#include <hip/hip_runtime.h>
#include <stdint.h>

#define N_TOK 8192
#define DDIM 1024
#define FDIM 4096
#define NEXP 8
#define MAXB1 72                 // 256-row blocks: 16384 + 8*255 padded -> 72
#define MAX_ROWS (MAXB1 * 256)   // 18432

typedef _Float16 half8 __attribute__((ext_vector_type(8)));
typedef float floatx4 __attribute__((ext_vector_type(4)));

#define VMCNT(n) asm volatile("s_waitcnt vmcnt(" #n ")" ::: "memory")
#define LGKM0 asm volatile("s_waitcnt lgkmcnt(0)" ::: "memory")
#define MFMA16(a, b, c) __builtin_amdgcn_mfma_f32_16x16x32_f16(a, b, c, 0, 0, 0)

__device__ __forceinline__ void gload_lds16(const void* g, void* l) {
  __builtin_amdgcn_global_load_lds(
      (const __attribute__((address_space(1))) unsigned int*)(uintptr_t)g,
      (__attribute__((address_space(3))) unsigned int*)(uint32_t)(uintptr_t)l,
      16, 0, 0);
}

// fast exact-enough gelu: tanh form, max |dev| vs erf-gelu ~1e-3
__device__ __forceinline__ float gelu_fast(float v) {
  float u = v * (0.7978845608f + 0.0356774081f * v * v);
  float ev = __expf(2.f * u);
  float th = 1.f - 2.f / (ev + 1.f);  // tanh(u), safe at +/-inf
  return 0.5f * v * (1.f + th);
}

// ---- convert+transpose: fp32 src[R][C] -> fp16 dst[C][R], 64x64 tiles ------
__global__ __launch_bounds__(256) void conv_transpose(
    const float* __restrict__ src, _Float16* __restrict__ dst, int R, int C) {
  __shared__ float t[64][65];
  int e = blockIdx.z;
  const float* s = src + (size_t)e * R * C;
  _Float16* d = dst + (size_t)e * R * C;
  int c0 = blockIdx.x * 64, r0 = blockIdx.y * 64;
  int tid = threadIdx.x;
  int rl = tid >> 4, c4 = (tid & 15) * 4;
#pragma unroll
  for (int i = 0; i < 4; ++i) {
    float4 v = *(const float4*)(s + (size_t)(r0 + rl + i * 16) * C + c0 + c4);
    *(float4*)&t[rl + i * 16][c4] = v;
  }
  __syncthreads();
  int dr = tid >> 2, cc0 = (tid & 3) * 16;  // dst row = src col
#pragma unroll
  for (int h = 0; h < 2; ++h) {
    half8 o;
#pragma unroll
    for (int k = 0; k < 8; ++k) o[k] = (_Float16)t[cc0 + h * 8 + k][dr];
    *(half8*)(d + (size_t)(c0 + dr) * R + r0 + cc0 + h * 8) = o;
  }
}

// ---- router: logits, top-2, softmax(fp32). NO atomics (counts done later) --
__global__ __launch_bounds__(256) void router_kernel(
    const float* __restrict__ x, const float* __restrict__ rw,
    int* __restrict__ tok_e, float* __restrict__ tok_w) {
  __shared__ float srw[NEXP * DDIM];
  int tid = threadIdx.x;
  const float4* rw4 = (const float4*)rw;
  float4* srw4 = (float4*)srw;
#pragma unroll
  for (int i = 0; i < 8; ++i) srw4[tid + i * 256] = rw4[tid + i * 256];
  __syncthreads();

  int wv = tid >> 6, l = tid & 63;
  int t = blockIdx.x * 4 + wv;
  const float4* xr = (const float4*)(x + (size_t)t * DDIM + l * 16);
  float4 xv[4];
#pragma unroll
  for (int i = 0; i < 4; ++i) xv[i] = xr[i];

  float logit[NEXP];
#pragma unroll
  for (int e = 0; e < NEXP; ++e) {
    const float4* wr4 = (const float4*)(srw + e * DDIM + l * 16);
    float acc = 0.f;
#pragma unroll
    for (int i = 0; i < 4; ++i) {
      float4 w4 = wr4[i];
      acc += xv[i].x * w4.x + xv[i].y * w4.y + xv[i].z * w4.z + xv[i].w * w4.w;
    }
#pragma unroll
    for (int off = 32; off > 0; off >>= 1) acc += __shfl_xor(acc, off);
    logit[e] = acc;
  }
  if (l == 0) {
    int i1 = 0;
    float v1 = logit[0];
#pragma unroll
    for (int e = 1; e < NEXP; ++e)
      if (logit[e] > v1) { v1 = logit[e]; i1 = e; }
    int i2 = -1;
    float v2 = -1e30f;
#pragma unroll
    for (int e = 0; e < NEXP; ++e)
      if (e != i1 && logit[e] > v2) { v2 = logit[e]; i2 = e; }
    float ex = expf(v2 - v1);  // v2 <= v1
    float denom = 1.f + ex;
    tok_e[2 * t] = i1;
    tok_e[2 * t + 1] = i2;
    tok_w[2 * t] = 1.f / denom;
    tok_w[2 * t + 1] = ex / denom;
  }
}

// ---- count: LDS histogram of tok_e -> meta[0..7] (8 atomics per block) -----
__global__ __launch_bounds__(256) void count_kernel(const int* __restrict__ tok_e,
                                                    int* __restrict__ meta) {
  __shared__ int h[NEXP];
  int tid = threadIdx.x;
  if (tid < NEXP) h[tid] = 0;
  __syncthreads();
  int idx = blockIdx.x * 512 + tid;  // grid 32 x 256, 2 pairs per thread
  atomicAdd(&h[tok_e[idx]], 1);
  atomicAdd(&h[tok_e[idx + 256]], 1);
  __syncthreads();
  if (tid < NEXP) atomicAdd(&meta[tid], h[tid]);
}

// ---- offsets: 256-padded segments + block->expert table --------------------
__global__ void offsets_kernel(int* meta) {
  __shared__ int seg[NEXP + 1];
  int l = threadIdx.x;
  if (l == 0) {
    int s = 0;
    for (int e = 0; e < NEXP; ++e) {
      seg[e] = s;
      meta[16 + e] = s;
      meta[8 + e] = s;  // fill cursor starts at segment base
      s += (meta[e] + 255) & ~255;
    }
    seg[NEXP] = s;
    meta[16 + NEXP] = s;
  }
  __syncthreads();
  for (int b = l; b < MAXB1; b += 64) {
    int row = b * 256, ee = -1;
#pragma unroll
    for (int e = 0; e < NEXP; ++e)
      if (row >= seg[e] && row < seg[e + 1]) ee = e;
    meta[32 + b] = ee;
  }
}

// ---- gather: wave-aggregated position assignment (8 atomics per wave) ------
__global__ __launch_bounds__(256) void gather_kernel(
    const int* __restrict__ tok_e, int* meta,
    int* __restrict__ row_map, int* __restrict__ inv_pos) {
  int p = blockIdx.x * 256 + threadIdx.x;  // 0..16383
  int e = tok_e[p];
  int lane = threadIdx.x & 63;
  unsigned long long lt = (lane == 63) ? ~0ull >> 1 : (1ull << lane) - 1;
  int pos = 0;
#pragma unroll
  for (int ee = 0; ee < NEXP; ++ee) {
    unsigned long long mask = __ballot(e == ee);
    if (mask) {
      int leader = __ffsll((long long)mask) - 1;
      int cnt = __popcll(mask);
      int base = 0;
      if (lane == leader) base = atomicAdd(&meta[8 + ee], cnt);
      base = __shfl(base, leader);
      if (e == ee) pos = base + __popcll(mask & lt);
    }
  }
  row_map[pos] = p >> 1;
  inv_pos[p] = pos;
}

// ---- Xg fill: gather x rows as fp16 (zeros for pads) -----------------------
__global__ void xg_fill_kernel(const float* __restrict__ x,
                               const int* __restrict__ row_map,
                               _Float16* __restrict__ Xg) {
  int r = blockIdx.x, t = threadIdx.x;
  int n = row_map[r];
  half8 h = {0, 0, 0, 0, 0, 0, 0, 0};
  if (n >= 0) {
    const float4* s = (const float4*)(x + (size_t)n * DDIM + t * 8);
    float4 a = s[0], b = s[1];
    h[0] = (_Float16)a.x; h[1] = (_Float16)a.y;
    h[2] = (_Float16)a.z; h[3] = (_Float16)a.w;
    h[4] = (_Float16)b.x; h[5] = (_Float16)b.y;
    h[6] = (_Float16)b.z; h[7] = (_Float16)b.w;
  }
  *(half8*)(Xg + (size_t)r * DDIM + t * 8) = h;
}

// ---- grouped GEMM, 256x256x64, 8 waves, 4-phase counted-vmcnt pipeline -----
// XCD-pure supergroups (r11): logical = (bid%8)*(nb/8)+bid/8; groups of 16
// logical ids (4 bx x 4 c) sit on one XCD -> 4MB operand set per L2.
template <int EPI, int LDA, int LDB>
__global__ __launch_bounds__(512, 2) void gemmG(
    const _Float16* __restrict__ A, const _Float16* __restrict__ Bbase,
    const int* __restrict__ be, int nbx, int nt, long long b_estride,
    size_t kqk, _Float16* __restrict__ Hout, int ldh,
    _Float16* __restrict__ Yq, size_t yzstride, int accum) {
  // ---- XCD-pure supergroup mapping ----
  int bid = blockIdx.x, nb = gridDim.x;
  int logical = (bid & 7) * (nb >> 3) + (bid >> 3);  // nb % 8 == 0 always
  int g = logical >> 4, r = logical & 15;
  int ngx = nbx >> 2;
  int gx = g % ngx, gy = g / ngx;
  int bx = gx * 4 + (r & 3);
  int c = gy * 4 + (r >> 2);
  int e = be[bx];
  if (e < 0) return;
  int by, bz;
  if (EPI == 1) { by = c & 3; bz = c >> 2; } else { by = c; bz = 0; }

  __shared__ __align__(16) _Float16 sA[2][256 * 64];
  __shared__ __align__(16) _Float16 sB[2][256 * 64];

  int tid = threadIdx.x, l = tid & 63, wid = tid >> 6;
  int wm = wid >> 2, wn = wid & 3;
  int rbA = wm * 128 + (l & 15);
  int cbB = wn * 64 + (l & 15);
  int sw = (l & 7) << 4;
  int ko0 = (((l >> 4) << 4) ^ sw) >> 1;         // fp16 elems, kk=0
  int ko1 = ((64 + ((l >> 4) << 4)) ^ sw) >> 1;  // kk=1
  int srow = tid >> 3;                           // 0..63 within a 64-row chunk
  int scol = ((((tid & 7) << 4) ^ ((srow & 7) << 4)) >> 1);

  // hoisted per-thread stage bases (compile-time strides -> shifts, LICM'd)
  const _Float16* Ab = A + (size_t)bx * 256 * LDA + (size_t)bz * kqk +
                       (size_t)srow * LDA + scol;
  const _Float16* Bb = Bbase + (size_t)e * b_estride + (size_t)by * 256 * LDB +
                       (size_t)bz * kqk + (size_t)srow * LDB + scol;

  floatx4 acc[8][4] = {};

  auto stA = [&](int t, int half) {  // A chunks {half, half+2} of tile t
    const _Float16* src = Ab + (size_t)t * 64;
    _Float16* dst = sA[t & 1];
    gload_lds16(src + half * (64 * LDA), dst + half * 4096 + tid * 8);
    gload_lds16(src + (half + 2) * (64 * LDA), dst + (half + 2) * 4096 + tid * 8);
  };
  auto stB = [&](int t, int c0) {  // B chunks {c0, c0+1} of tile t
    const _Float16* src = Bb + (size_t)t * 64;
    _Float16* dst = sB[t & 1];
    gload_lds16(src + c0 * (64 * LDB), dst + c0 * 4096 + tid * 8);
    gload_lds16(src + (c0 + 1) * (64 * LDB), dst + (c0 + 1) * 4096 + tid * 8);
  };

  // prologue: B(0), A(0), B(1), A(1)-half0  (14 loads; drain oldest 8)
  stB(0, 0); stB(0, 2);
  stA(0, 0);
  stA(0, 1);
  stB(1, 0); stB(1, 2);
  stA(1, 0);
  VMCNT(6);
  __builtin_amdgcn_s_barrier();

  for (int t = 0; t < nt; ++t) {
    const _Float16* sAb = sA[t & 1];
    const _Float16* sBb = sB[t & 1];
    half8 bf[4][2], af[4];

    // ---- phase 0: read B(all)+A(mh0,kk0); stage a1(t+1) ----
#pragma unroll
    for (int n = 0; n < 4; ++n) {
      bf[n][0] = *(const half8*)&sBb[(cbB + n * 16) * 64 + ko0];
      bf[n][1] = *(const half8*)&sBb[(cbB + n * 16) * 64 + ko1];
    }
#pragma unroll
    for (int m = 0; m < 4; ++m) af[m] = *(const half8*)&sAb[(rbA + m * 16) * 64 + ko0];
    if (t + 1 < nt) stA(t + 1, 1);
    __builtin_amdgcn_s_barrier();
    LGKM0; __builtin_amdgcn_sched_barrier(0);
    __builtin_amdgcn_s_setprio(1);
#pragma unroll
    for (int m = 0; m < 4; ++m)
#pragma unroll
      for (int n = 0; n < 4; ++n) acc[m][n] = MFMA16(af[m], bf[n][0], acc[m][n]);
    __builtin_amdgcn_s_setprio(0);
    __builtin_amdgcn_s_barrier();
    // ---- phase 1: read A(mh0,kk1); stage B(t+2)[0,1] ----
#pragma unroll
    for (int m = 0; m < 4; ++m) af[m] = *(const half8*)&sAb[(rbA + m * 16) * 64 + ko1];
    if (t + 2 < nt) stB(t + 2, 0);
    VMCNT(10);
    __builtin_amdgcn_s_barrier();
    LGKM0; __builtin_amdgcn_sched_barrier(0);
    __builtin_amdgcn_s_setprio(1);
#pragma unroll
    for (int m = 0; m < 4; ++m)
#pragma unroll
      for (int n = 0; n < 4; ++n) acc[m][n] = MFMA16(af[m], bf[n][1], acc[m][n]);
    __builtin_amdgcn_s_setprio(0);
    __builtin_amdgcn_s_barrier();
    // ---- phase 2: read A(mh1,kk0); stage B(t+2)[2,3] ----
#pragma unroll
    for (int m = 0; m < 4; ++m) af[m] = *(const half8*)&sAb[(rbA + 64 + m * 16) * 64 + ko0];
    if (t + 2 < nt) stB(t + 2, 2);
    __builtin_amdgcn_s_barrier();
    LGKM0; __builtin_amdgcn_sched_barrier(0);
    __builtin_amdgcn_s_setprio(1);
#pragma unroll
    for (int m = 0; m < 4; ++m)
#pragma unroll
      for (int n = 0; n < 4; ++n) acc[4 + m][n] = MFMA16(af[m], bf[n][0], acc[4 + m][n]);
    __builtin_amdgcn_s_setprio(0);
    __builtin_amdgcn_s_barrier();
    // ---- phase 3: read A(mh1,kk1); stage a0(t+2); VMCNT(6)/(0 at tail) ----
#pragma unroll
    for (int m = 0; m < 4; ++m) af[m] = *(const half8*)&sAb[(rbA + 64 + m * 16) * 64 + ko1];
    if (t + 2 < nt) {
      stA(t + 2, 0);
      VMCNT(6);
    } else {
      VMCNT(0);  // tail: confirm everything (incl. a1(t+1) staged at p0)
    }
    __builtin_amdgcn_s_barrier();
    LGKM0; __builtin_amdgcn_sched_barrier(0);
    __builtin_amdgcn_s_setprio(1);
#pragma unroll
    for (int m = 0; m < 4; ++m)
#pragma unroll
      for (int n = 0; n < 4; ++n) acc[4 + m][n] = MFMA16(af[m], bf[n][1], acc[4 + m][n]);
    __builtin_amdgcn_s_setprio(0);
    __builtin_amdgcn_s_barrier();
  }

  if (EPI == 0) {
#pragma unroll
    for (int m = 0; m < 8; ++m) {
#pragma unroll
      for (int j = 0; j < 4; ++j) {
        size_t rr = (size_t)bx * 256 + wm * 128 + m * 16 + (l >> 4) * 4 + j;
        _Float16* hp = Hout + rr * ldh + (size_t)by * 256 + wn * 64 + (l & 15);
#pragma unroll
        for (int n = 0; n < 4; ++n) hp[n * 16] = (_Float16)gelu_fast(acc[m][n][j]);
      }
    }
  } else {
    _Float16* Yz = Yq + (size_t)bz * yzstride;
#pragma unroll
    for (int m = 0; m < 8; ++m) {
#pragma unroll
      for (int j = 0; j < 4; ++j) {
        size_t rr = (size_t)bx * 256 + wm * 128 + m * 16 + (l >> 4) * 4 + j;
        _Float16* yp = Yz + rr * DDIM + (size_t)by * 256 + wn * 64 + (l & 15);
        if (accum) {
#pragma unroll
          for (int n = 0; n < 4; ++n)
            yp[n * 16] = (_Float16)((float)yp[n * 16] + acc[m][n][j]);
        } else {
#pragma unroll
          for (int n = 0; n < 4; ++n) yp[n * 16] = (_Float16)acc[m][n][j];
        }
      }
    }
  }
}

// ---- combine: out[t] = sum_k ( w0*Yq[k][pos0] + w1*Yq[k][pos1] ) -----------
__global__ __launch_bounds__(128) void combine_kernel(
    const _Float16* __restrict__ Yq, int KQ, size_t yz,
    const int* __restrict__ inv_pos, const float* __restrict__ tok_w,
    float* __restrict__ out) {
  int t = blockIdx.x, l = threadIdx.x;
  int p0 = inv_pos[2 * t], p1 = inv_pos[2 * t + 1];
  float w0 = tok_w[2 * t], w1 = tok_w[2 * t + 1];
  float s[8] = {0, 0, 0, 0, 0, 0, 0, 0};
  for (int k = 0; k < KQ; ++k) {
    half8 h0 = *(const half8*)(Yq + k * yz + (size_t)p0 * DDIM + l * 8);
    half8 h1 = *(const half8*)(Yq + k * yz + (size_t)p1 * DDIM + l * 8);
#pragma unroll
    for (int j = 0; j < 8; ++j) s[j] += w0 * (float)h0[j] + w1 * (float)h1[j];
  }
  float4* o = (float4*)(out + (size_t)t * DDIM) + l * 2;
  o[0] = make_float4(s[0], s[1], s[2], s[3]);
  o[1] = make_float4(s[4], s[5], s[6], s[7]);
}

// ---------------- launch -----------------------------------------------------
extern "C" void kernel_launch(void* const* d_in, const int* in_sizes, int n_in,
                              void* d_out, int out_size, void* d_ws, size_t ws_size,
                              hipStream_t stream) {
  const float* x = (const float*)d_in[0];
  const float* rw = (const float*)d_in[1];
  const float* w1 = (const float*)d_in[2];
  const float* w2 = (const float*)d_in[3];
  float* out = (float*)d_out;

  char* base = (char*)d_ws;
  size_t off = 0;
  auto alloc = [&](size_t bytes) {
    void* p = base + off;
    off += (bytes + 255) & ~(size_t)255;
    return p;
  };
  const size_t SZ_W = (size_t)NEXP * FDIM * DDIM * 2;   // 64 MB each
  const size_t SZ_XG = (size_t)MAX_ROWS * DDIM * 2;     // ~37.8 MB
  const size_t SZ_YZ = (size_t)MAX_ROWS * DDIM * 2;     // per K-slab (fp16)

  // small buffers first (survive any aliasing)
  int* row_map = (int*)alloc(MAX_ROWS * 4);
  int* inv_pos = (int*)alloc(N_TOK * 2 * 4);
  int* tok_e = (int*)alloc(N_TOK * 2 * 4);
  float* tok_w = (float*)alloc(N_TOK * 2 * 4);
  int* meta = (int*)alloc(1024);
  _Float16* w2t = (_Float16*)alloc(SZ_W);
  size_t head = off;

  int NC = 1, KQ = 4;
  _Float16 *w1t, *Xg, *H, *Yq;
  size_t hsz1 = (size_t)MAX_ROWS * FDIM * 2;
  if (head + hsz1 + SZ_W + SZ_XG + 4 * SZ_YZ <= ws_size) {
    H = (_Float16*)alloc(hsz1);
    w1t = (_Float16*)alloc(SZ_W);
    Xg = (_Float16*)alloc(SZ_XG);
    Yq = (_Float16*)alloc(4 * SZ_YZ);
  } else if (head + hsz1 + SZ_W + SZ_XG <= ws_size &&
             head + hsz1 + 4 * SZ_YZ <= ws_size) {
    // alias: Yq overlays w1t+Xg+tail (w1t/Xg dead before GEMM2 at NC=1)
    H = (_Float16*)alloc(hsz1);
    w1t = (_Float16*)alloc(SZ_W);
    Xg = (_Float16*)alloc(SZ_XG);
    Yq = w1t;
  } else {
    NC = (head + (size_t)MAX_ROWS * (FDIM / 2) * 2 + SZ_W + SZ_XG + 2 * SZ_YZ <= ws_size) ? 2 : 4;
    KQ = 4 / NC;
    H = (_Float16*)alloc((size_t)MAX_ROWS * (FDIM / NC) * 2);
    w1t = (_Float16*)alloc(SZ_W);
    Xg = (_Float16*)alloc(SZ_XG);
    Yq = (_Float16*)alloc((size_t)KQ * SZ_YZ);
  }
  int Fc = FDIM / NC;

  hipMemsetAsync(meta, 0, 64, stream);                  // counts + fill
  hipMemsetAsync(row_map, 0xFF, MAX_ROWS * 4, stream);  // -1 sentinels

  conv_transpose<<<dim3(FDIM / 64, DDIM / 64, NEXP), 256, 0, stream>>>(w1, w1t, DDIM, FDIM);
  conv_transpose<<<dim3(DDIM / 64, FDIM / 64, NEXP), 256, 0, stream>>>(w2, w2t, FDIM, DDIM);
  router_kernel<<<N_TOK / 4, 256, 0, stream>>>(x, rw, tok_e, tok_w);
  count_kernel<<<32, 256, 0, stream>>>(tok_e, meta);
  offsets_kernel<<<1, 64, 0, stream>>>(meta);
  gather_kernel<<<N_TOK * 2 / 256, 256, 0, stream>>>(tok_e, meta, row_map, inv_pos);
  xg_fill_kernel<<<MAX_ROWS, 128, 0, stream>>>(x, row_map, Xg);

  const int* be = meta + 32;
  size_t kqk = (size_t)Fc / KQ;   // K elems per K-slab of GEMM2
  int nt2 = (int)(kqk / 64);      // 16 in all ladder configs
  for (int cc = 0; cc < NC; ++cc) {
    // GEMM1: Xg[M,1024] x w1t[e][Fc,1024]^T -> gelu -> H[M,Fc]
    gemmG<0, DDIM, DDIM><<<dim3(MAXB1 * (Fc / 256)), 512, 0, stream>>>(
        Xg, w1t + (size_t)cc * Fc * DDIM, be, MAXB1,
        DDIM / 64, (long long)FDIM * DDIM, 0, H, Fc, nullptr, 0, 0);
    // GEMM2: H[M,Fc] x w2t[e][1024,F(slice cc)]^T, K split KQ ways -> Yq
    if (NC == 1)
      gemmG<1, 4096, FDIM><<<dim3(MAXB1 * 4 * KQ), 512, 0, stream>>>(
          H, w2t + (size_t)cc * Fc, be, MAXB1, nt2,
          (long long)DDIM * FDIM, kqk, nullptr, 0, Yq, SZ_YZ / 2, cc > 0);
    else if (NC == 2)
      gemmG<1, 2048, FDIM><<<dim3(MAXB1 * 4 * KQ), 512, 0, stream>>>(
          H, w2t + (size_t)cc * Fc, be, MAXB1, nt2,
          (long long)DDIM * FDIM, kqk, nullptr, 0, Yq, SZ_YZ / 2, cc > 0);
    else
      gemmG<1, 1024, FDIM><<<dim3(MAXB1 * 4 * KQ), 512, 0, stream>>>(
          H, w2t + (size_t)cc * Fc, be, MAXB1, nt2,
          (long long)DDIM * FDIM, kqk, nullptr, 0, Yq, SZ_YZ / 2, cc > 0);
  }
  combine_kernel<<<N_TOK, 128, 0, stream>>>(Yq, KQ, SZ_YZ / 2, inv_pos, tok_w, out);
}

// Round 13
// 509.571 us; speedup vs baseline: 1.5799x; 1.1178x over previous
//
#include <hip/hip_runtime.h>
#include <stdint.h>

#define N_TOK 8192
#define DDIM 1024
#define FDIM 4096
#define NEXP 8
#define MAXB 144                 // 128-row blocks: 137 used + pad to %8==0
#define MAX_ROWS (MAXB * 128)    // 18432

typedef _Float16 half8 __attribute__((ext_vector_type(8)));
typedef float floatx4 __attribute__((ext_vector_type(4)));

#define MFMA16(a, b, c) __builtin_amdgcn_mfma_f32_16x16x32_f16(a, b, c, 0, 0, 0)

__device__ __forceinline__ void gload_lds16(const void* g, void* l) {
  __builtin_amdgcn_global_load_lds(
      (const __attribute__((address_space(1))) unsigned int*)(uintptr_t)g,
      (__attribute__((address_space(3))) unsigned int*)(uint32_t)(uintptr_t)l,
      16, 0, 0);
}

// fast exact-enough gelu: tanh form, max |dev| vs erf-gelu ~1e-3
__device__ __forceinline__ float gelu_fast(float v) {
  float u = v * (0.7978845608f + 0.0356774081f * v * v);
  float ev = __expf(2.f * u);
  float th = 1.f - 2.f / (ev + 1.f);  // tanh(u), safe at +/-inf
  return 0.5f * v * (1.f + th);
}

// ---- fused convert+transpose for BOTH weights (one dispatch) ---------------
// z<8: w1[z] (R=1024,C=4096); z>=8: w2[z-8] (R=4096,C=1024).
__global__ __launch_bounds__(256) void conv_transpose2(
    const float* __restrict__ w1, _Float16* __restrict__ w1t,
    const float* __restrict__ w2, _Float16* __restrict__ w2t) {
  __shared__ float t[64][65];
  int z = blockIdx.z;
  const float* s;
  _Float16* d;
  int R, C, c0, r0;
  if (z < 8) {
    s = w1 + (size_t)z * DDIM * FDIM;
    d = w1t + (size_t)z * FDIM * DDIM;
    R = DDIM; C = FDIM;
    c0 = blockIdx.x * 64; r0 = blockIdx.y * 64;
  } else {
    s = w2 + (size_t)(z - 8) * FDIM * DDIM;
    d = w2t + (size_t)(z - 8) * DDIM * FDIM;
    R = FDIM; C = DDIM;
    c0 = blockIdx.y * 64; r0 = blockIdx.x * 64;
  }
  int tid = threadIdx.x;
  int rl = tid >> 4, c4 = (tid & 15) * 4;
#pragma unroll
  for (int i = 0; i < 4; ++i) {
    float4 v = *(const float4*)(s + (size_t)(r0 + rl + i * 16) * C + c0 + c4);
    *(float4*)&t[rl + i * 16][c4] = v;
  }
  __syncthreads();
  int dr = tid >> 2, cc0 = (tid & 3) * 16;  // dst row = src col
#pragma unroll
  for (int h = 0; h < 2; ++h) {
    half8 o;
#pragma unroll
    for (int k = 0; k < 8; ++k) o[k] = (_Float16)t[cc0 + h * 8 + k][dr];
    *(half8*)(d + (size_t)(c0 + dr) * R + r0 + cc0 + h * 8) = o;
  }
}

// ---- router: logits, top-2, softmax(fp32). No atomics ----------------------
__global__ __launch_bounds__(256) void router_kernel(
    const float* __restrict__ x, const float* __restrict__ rw,
    int* __restrict__ tok_e, float* __restrict__ tok_w) {
  __shared__ float srw[NEXP * DDIM];
  int tid = threadIdx.x;
  const float4* rw4 = (const float4*)rw;
  float4* srw4 = (float4*)srw;
#pragma unroll
  for (int i = 0; i < 8; ++i) srw4[tid + i * 256] = rw4[tid + i * 256];
  __syncthreads();

  int wv = tid >> 6, l = tid & 63;
  int t = blockIdx.x * 4 + wv;
  const float4* xr = (const float4*)(x + (size_t)t * DDIM + l * 16);
  float4 xv[4];
#pragma unroll
  for (int i = 0; i < 4; ++i) xv[i] = xr[i];

  float logit[NEXP];
#pragma unroll
  for (int e = 0; e < NEXP; ++e) {
    const float4* wr4 = (const float4*)(srw + e * DDIM + l * 16);
    float acc = 0.f;
#pragma unroll
    for (int i = 0; i < 4; ++i) {
      float4 w4 = wr4[i];
      acc += xv[i].x * w4.x + xv[i].y * w4.y + xv[i].z * w4.z + xv[i].w * w4.w;
    }
#pragma unroll
    for (int off = 32; off > 0; off >>= 1) acc += __shfl_xor(acc, off);
    logit[e] = acc;
  }
  if (l == 0) {
    int i1 = 0;
    float v1 = logit[0];
#pragma unroll
    for (int e = 1; e < NEXP; ++e)
      if (logit[e] > v1) { v1 = logit[e]; i1 = e; }
    int i2 = -1;
    float v2 = -1e30f;
#pragma unroll
    for (int e = 0; e < NEXP; ++e)
      if (e != i1 && logit[e] > v2) { v2 = logit[e]; i2 = e; }
    float ex = expf(v2 - v1);  // v2 <= v1
    float denom = 1.f + ex;
    tok_e[2 * t] = i1;
    tok_e[2 * t + 1] = i2;
    tok_w[2 * t] = 1.f / denom;
    tok_w[2 * t + 1] = ex / denom;
  }
}

// ---- count: LDS histogram of tok_e -> meta[0..7] (8 atomics per block) -----
__global__ __launch_bounds__(256) void count_kernel(const int* __restrict__ tok_e,
                                                    int* __restrict__ meta) {
  __shared__ int h[NEXP];
  int tid = threadIdx.x;
  if (tid < NEXP) h[tid] = 0;
  __syncthreads();
  int idx = blockIdx.x * 512 + tid;  // grid 32 x 256, 2 pairs per thread
  atomicAdd(&h[tok_e[idx]], 1);
  atomicAdd(&h[tok_e[idx + 256]], 1);
  __syncthreads();
  if (tid < NEXP) atomicAdd(&meta[tid], h[tid]);
}

// ---- offsets: 128-padded segments + block->expert table --------------------
__global__ void offsets_kernel(int* meta) {
  __shared__ int seg[NEXP + 1];
  int l = threadIdx.x;
  if (l == 0) {
    int s = 0;
    for (int e = 0; e < NEXP; ++e) {
      seg[e] = s;
      meta[16 + e] = s;
      meta[8 + e] = s;  // fill cursor starts at segment base
      s += (meta[e] + 127) & ~127;
    }
    seg[NEXP] = s;
    meta[16 + NEXP] = s;
  }
  __syncthreads();
  for (int b = l; b < MAXB; b += 64) {
    int row = b * 128, ee = -1;
#pragma unroll
    for (int e = 0; e < NEXP; ++e)
      if (row >= seg[e] && row < seg[e + 1]) ee = e;
    meta[32 + b] = ee;
  }
}

// ---- gather: wave-aggregated position assignment (8 atomics per wave) ------
__global__ __launch_bounds__(256) void gather_kernel(
    const int* __restrict__ tok_e, int* meta,
    int* __restrict__ row_map, int* __restrict__ inv_pos) {
  int p = blockIdx.x * 256 + threadIdx.x;  // 0..16383
  int e = tok_e[p];
  int lane = threadIdx.x & 63;
  unsigned long long lt = (lane == 63) ? ~0ull >> 1 : (1ull << lane) - 1;
  int pos = 0;
#pragma unroll
  for (int ee = 0; ee < NEXP; ++ee) {
    unsigned long long mask = __ballot(e == ee);
    if (mask) {
      int leader = __ffsll((long long)mask) - 1;
      int cnt = __popcll(mask);
      int base = 0;
      if (lane == leader) base = atomicAdd(&meta[8 + ee], cnt);
      base = __shfl(base, leader);
      if (e == ee) pos = base + __popcll(mask & lt);
    }
  }
  row_map[pos] = p >> 1;
  inv_pos[p] = pos;
}

// ---- Xg fill: gather x rows as fp16 (zeros for pads) -----------------------
__global__ void xg_fill_kernel(const float* __restrict__ x,
                               const int* __restrict__ row_map,
                               _Float16* __restrict__ Xg) {
  int r = blockIdx.x, t = threadIdx.x;
  int n = row_map[r];
  half8 h = {0, 0, 0, 0, 0, 0, 0, 0};
  if (n >= 0) {
    const float4* s = (const float4*)(x + (size_t)n * DDIM + t * 8);
    float4 a = s[0], b = s[1];
    h[0] = (_Float16)a.x; h[1] = (_Float16)a.y;
    h[2] = (_Float16)a.z; h[3] = (_Float16)a.w;
    h[4] = (_Float16)b.x; h[5] = (_Float16)b.y;
    h[6] = (_Float16)b.z; h[7] = (_Float16)b.w;
  }
  *(half8*)(Xg + (size_t)r * DDIM + t * 8) = h;
}

// ---- grouped GEMM, m97-style: 128x128x64, 4 waves, single 32KB LDS buffer,
// 3 blocks/CU TLP (block-level convoy overlapped ACROSS blocks, not within).
// XCD-pure 4x4 supergroups (2MB operand set per L2); XOR-swizzled LDS
// (inverse-swizzled global source + swizzled ds_read, both-sides rule).
// EPI=0: gelu -> Hout fp16. EPI=1: fp16 store/accum into Yq K-slab.
template <int EPI, int LDA, int LDB>
__global__ __launch_bounds__(256, 3) void gemmT(
    const _Float16* __restrict__ A, const _Float16* __restrict__ Bbase,
    const int* __restrict__ be, int nbx, int nt, long long b_estride,
    size_t kqk, _Float16* __restrict__ Hout, int ldh,
    _Float16* __restrict__ Yq, size_t yzstride, int accum) {
  // XCD-pure supergroup mapping (nb % 8 == 0; (nb/8) % 16 == 0)
  int bid = blockIdx.x, nb = gridDim.x;
  int logical = (bid & 7) * (nb >> 3) + (bid >> 3);
  int g = logical >> 4, r = logical & 15;
  int ngx = nbx >> 2;
  int gx = g % ngx, gy = g / ngx;
  int bx = gx * 4 + (r & 3);
  int c = gy * 4 + (r >> 2);
  int e = be[bx];
  if (e < 0) return;
  int by, bz;
  if (EPI == 1) { by = c & 7; bz = c >> 3; } else { by = c; bz = 0; }

  __shared__ __align__(16) _Float16 sA[128 * 64];
  __shared__ __align__(16) _Float16 sB[128 * 64];

  int tid = threadIdx.x, l = tid & 63, wid = tid >> 6;
  int wm = wid >> 1, wn = wid & 1;           // 2M x 2N waves, 64x64 each
  int rbA = wm * 64 + (l & 15);
  int cbB = wn * 64 + (l & 15);
  int sw = (l & 7) << 4;
  int ko0 = (((l >> 4) << 4) ^ sw) >> 1;         // fp16 elems, kk=0
  int ko1 = ((64 + ((l >> 4) << 4)) ^ sw) >> 1;  // kk=1
  int srow = tid >> 3;                           // 0..31
  int scol = ((((tid & 7) << 4) ^ ((srow & 7) << 4)) >> 1);

  const _Float16* Ab = A + (size_t)bx * 128 * LDA + (size_t)bz * kqk +
                       (size_t)srow * LDA + scol;
  const _Float16* Bb = Bbase + (size_t)e * b_estride + (size_t)by * 128 * LDB +
                       (size_t)bz * kqk + (size_t)srow * LDB + scol;

  floatx4 acc[4][4] = {};

  for (int t = 0; t < nt; ++t) {
    const _Float16* As = Ab + (size_t)t * 64;
    const _Float16* Bs = Bb + (size_t)t * 64;
#pragma unroll
    for (int i = 0; i < 4; ++i) {       // rows srow+32i; (row&7)==(srow&7)
      gload_lds16(As + i * (32 * LDA), sA + i * 2048 + tid * 8);
      gload_lds16(Bs + i * (32 * LDB), sB + i * 2048 + tid * 8);
    }
    __syncthreads();  // compiler drains vmcnt before barrier

    half8 bf[4][2];
#pragma unroll
    for (int n = 0; n < 4; ++n) {
      bf[n][0] = *(const half8*)&sB[(cbB + n * 16) * 64 + ko0];
      bf[n][1] = *(const half8*)&sB[(cbB + n * 16) * 64 + ko1];
    }
#pragma unroll
    for (int m = 0; m < 4; ++m) {
      half8 a0 = *(const half8*)&sA[(rbA + m * 16) * 64 + ko0];
      half8 a1 = *(const half8*)&sA[(rbA + m * 16) * 64 + ko1];
#pragma unroll
      for (int n = 0; n < 4; ++n) {
        acc[m][n] = MFMA16(a0, bf[n][0], acc[m][n]);
        acc[m][n] = MFMA16(a1, bf[n][1], acc[m][n]);
      }
    }
    __syncthreads();  // before next tile overwrites LDS
  }

  if (EPI == 0) {
#pragma unroll
    for (int m = 0; m < 4; ++m) {
#pragma unroll
      for (int j = 0; j < 4; ++j) {
        size_t rr = (size_t)bx * 128 + wm * 64 + m * 16 + (l >> 4) * 4 + j;
        _Float16* hp = Hout + rr * ldh + (size_t)by * 128 + wn * 64 + (l & 15);
#pragma unroll
        for (int n = 0; n < 4; ++n) hp[n * 16] = (_Float16)gelu_fast(acc[m][n][j]);
      }
    }
  } else {
    _Float16* Yz = Yq + (size_t)bz * yzstride;
#pragma unroll
    for (int m = 0; m < 4; ++m) {
#pragma unroll
      for (int j = 0; j < 4; ++j) {
        size_t rr = (size_t)bx * 128 + wm * 64 + m * 16 + (l >> 4) * 4 + j;
        _Float16* yp = Yz + rr * DDIM + (size_t)by * 128 + wn * 64 + (l & 15);
        if (accum) {
#pragma unroll
          for (int n = 0; n < 4; ++n)
            yp[n * 16] = (_Float16)((float)yp[n * 16] + acc[m][n][j]);
        } else {
#pragma unroll
          for (int n = 0; n < 4; ++n) yp[n * 16] = (_Float16)acc[m][n][j];
        }
      }
    }
  }
}

// ---- combine: out[t] = sum_k ( w0*Yq[k][pos0] + w1*Yq[k][pos1] ) -----------
__global__ __launch_bounds__(128) void combine_kernel(
    const _Float16* __restrict__ Yq, int KQ, size_t yz,
    const int* __restrict__ inv_pos, const float* __restrict__ tok_w,
    float* __restrict__ out) {
  int t = blockIdx.x, l = threadIdx.x;
  int p0 = inv_pos[2 * t], p1 = inv_pos[2 * t + 1];
  float w0 = tok_w[2 * t], w1 = tok_w[2 * t + 1];
  float s[8] = {0, 0, 0, 0, 0, 0, 0, 0};
  for (int k = 0; k < KQ; ++k) {
    half8 h0 = *(const half8*)(Yq + k * yz + (size_t)p0 * DDIM + l * 8);
    half8 h1 = *(const half8*)(Yq + k * yz + (size_t)p1 * DDIM + l * 8);
#pragma unroll
    for (int j = 0; j < 8; ++j) s[j] += w0 * (float)h0[j] + w1 * (float)h1[j];
  }
  float4* o = (float4*)(out + (size_t)t * DDIM) + l * 2;
  o[0] = make_float4(s[0], s[1], s[2], s[3]);
  o[1] = make_float4(s[4], s[5], s[6], s[7]);
}

// ---------------- launch -----------------------------------------------------
extern "C" void kernel_launch(void* const* d_in, const int* in_sizes, int n_in,
                              void* d_out, int out_size, void* d_ws, size_t ws_size,
                              hipStream_t stream) {
  const float* x = (const float*)d_in[0];
  const float* rw = (const float*)d_in[1];
  const float* w1 = (const float*)d_in[2];
  const float* w2 = (const float*)d_in[3];
  float* out = (float*)d_out;

  char* base = (char*)d_ws;
  size_t off = 0;
  auto alloc = [&](size_t bytes) {
    void* p = base + off;
    off += (bytes + 255) & ~(size_t)255;
    return p;
  };
  const size_t SZ_W = (size_t)NEXP * FDIM * DDIM * 2;   // 64 MB each
  const size_t SZ_XG = (size_t)MAX_ROWS * DDIM * 2;     // ~37.8 MB
  const size_t SZ_YZ = (size_t)MAX_ROWS * DDIM * 2;     // per K-slab (fp16)

  int* row_map = (int*)alloc(MAX_ROWS * 4);
  int* inv_pos = (int*)alloc(N_TOK * 2 * 4);
  int* tok_e = (int*)alloc(N_TOK * 2 * 4);
  float* tok_w = (float*)alloc(N_TOK * 2 * 4);
  int* meta = (int*)alloc(1024);
  _Float16* w2t = (_Float16*)alloc(SZ_W);
  size_t head = off;

  int NC = 1, KQ = 2;
  _Float16 *w1t, *Xg, *H, *Yq;
  size_t hsz1 = (size_t)MAX_ROWS * FDIM * 2;
  if (head + hsz1 + SZ_W + SZ_XG + 2 * SZ_YZ <= ws_size) {
    H = (_Float16*)alloc(hsz1);
    w1t = (_Float16*)alloc(SZ_W);
    Xg = (_Float16*)alloc(SZ_XG);
    Yq = (_Float16*)alloc(2 * SZ_YZ);
  } else if (head + hsz1 + SZ_W + SZ_XG <= ws_size &&
             head + hsz1 + 2 * SZ_YZ <= ws_size) {
    // alias: Yq overlays w1t+tail (w1t/Xg dead before GEMM2 at NC=1)
    H = (_Float16*)alloc(hsz1);
    w1t = (_Float16*)alloc(SZ_W);
    Xg = (_Float16*)alloc(SZ_XG);
    Yq = w1t;
  } else {
    NC = (head + (size_t)MAX_ROWS * (FDIM / 2) * 2 + SZ_W + SZ_XG + 2 * SZ_YZ <= ws_size) ? 2 : 4;
    KQ = NC == 2 ? 2 : 1;
    H = (_Float16*)alloc((size_t)MAX_ROWS * (FDIM / NC) * 2);
    w1t = (_Float16*)alloc(SZ_W);
    Xg = (_Float16*)alloc(SZ_XG);
    Yq = (_Float16*)alloc((size_t)KQ * SZ_YZ);
  }
  int Fc = FDIM / NC;

  hipMemsetAsync(meta, 0, 64, stream);                  // counts + fill
  hipMemsetAsync(row_map, 0xFF, MAX_ROWS * 4, stream);  // -1 sentinels

  conv_transpose2<<<dim3(64, 16, 16), 256, 0, stream>>>(w1, w1t, w2, w2t);
  router_kernel<<<N_TOK / 4, 256, 0, stream>>>(x, rw, tok_e, tok_w);
  count_kernel<<<32, 256, 0, stream>>>(tok_e, meta);
  offsets_kernel<<<1, 64, 0, stream>>>(meta);
  gather_kernel<<<N_TOK * 2 / 256, 256, 0, stream>>>(tok_e, meta, row_map, inv_pos);
  xg_fill_kernel<<<MAX_ROWS, 128, 0, stream>>>(x, row_map, Xg);

  const int* be = meta + 32;
  size_t kqk = (size_t)Fc / KQ;   // K elems per K-slab of GEMM2
  int nt2 = (int)(kqk / 64);
  for (int cc = 0; cc < NC; ++cc) {
    // GEMM1: Xg[M,1024] x w1t[e][Fc,1024]^T -> gelu -> H[M,Fc]
    gemmT<0, DDIM, DDIM><<<dim3(MAXB * (Fc / 128)), 256, 0, stream>>>(
        Xg, w1t + (size_t)cc * Fc * DDIM, be, MAXB,
        DDIM / 64, (long long)FDIM * DDIM, 0, H, Fc, nullptr, 0, 0);
    // GEMM2: H[M,Fc] x w2t[e][1024,F(slice cc)]^T, K split KQ ways -> Yq
    if (NC == 1)
      gemmT<1, 4096, FDIM><<<dim3(MAXB * 8 * KQ), 256, 0, stream>>>(
          H, w2t + (size_t)cc * Fc, be, MAXB, nt2,
          (long long)DDIM * FDIM, kqk, nullptr, 0, Yq, SZ_YZ / 2, cc > 0);
    else if (NC == 2)
      gemmT<1, 2048, FDIM><<<dim3(MAXB * 8 * KQ), 256, 0, stream>>>(
          H, w2t + (size_t)cc * Fc, be, MAXB, nt2,
          (long long)DDIM * FDIM, kqk, nullptr, 0, Yq, SZ_YZ / 2, cc > 0);
    else
      gemmT<1, 1024, FDIM><<<dim3(MAXB * 8 * KQ), 256, 0, stream>>>(
          H, w2t + (size_t)cc * Fc, be, MAXB, nt2,
          (long long)DDIM * FDIM, kqk, nullptr, 0, Yq, SZ_YZ / 2, cc > 0);
  }
  combine_kernel<<<N_TOK, 128, 0, stream>>>(Yq, KQ, SZ_YZ / 2, inv_pos, tok_w, out);
}